// Round 8
// baseline (485.469 us; speedup 1.0000x reference)
//
#include <hip/hip_runtime.h>

// Slot attention, MI355X. B=64,N=4096,S=8,D=256,H=512,ITERS=3.
#define BB 64
#define NN 4096
#define SS 8
#define DD 256
#define HH 512
#define NCH 8
#define CHK 512
#define LSP 516  // padded row stride (f32) for logits LDS

typedef __attribute__((ext_vector_type(4))) float f32x4;
typedef __attribute__((ext_vector_type(8))) short short8;
typedef __attribute__((ext_vector_type(8))) __bf16 bf16x8;

static __device__ __forceinline__ f32x4 MFMA(short8 a, short8 b, f32x4 c){
  return __builtin_amdgcn_mfma_f32_16x16x32_bf16(
      __builtin_bit_cast(bf16x8, a), __builtin_bit_cast(bf16x8, b), c, 0, 0, 0);
}

static __device__ __forceinline__ unsigned short f2bf(float f){
  unsigned int x = __builtin_bit_cast(unsigned int, f);
  x += 0x7FFFu + ((x >> 16) & 1u);
  return (unsigned short)(x >> 16);
}

static __device__ __forceinline__ unsigned int pk2(float a, float b){
  return (unsigned int)f2bf(a) | ((unsigned int)f2bf(b) << 16);
}

static __device__ __forceinline__ void gl_lds16(const void* g, void* l){
  __builtin_amdgcn_global_load_lds(
      (__attribute__((address_space(1))) const void*)g,
      (__attribute__((address_space(3))) void*)l, 16, 0, 0);
}

// ---- merged weight pack: W(E=ET*16, K) fp32 row-major -> bf16 MFMA fragments
struct PackDesc {
  const float* src[7];
  unsigned short* dst[7];
  int ET[7];
  int K[7];
  int blkStart[8];
};

__global__ void pack_all_kernel(PackDesc pd){
  int blk = blockIdx.x;
  int seg = 0;
  #pragma unroll
  for(int i = 1; i < 7; ++i) if(blk >= pd.blkStart[i]) seg = i;
  int tid = (blk - pd.blkStart[seg]) * 256 + threadIdx.x;
  int ET = pd.ET[seg], K = pd.K[seg];
  if(tid >= ET * 16 * K) return;
  int i    = tid & 7;
  int lane = (tid >> 3) & 63;
  int rest = tid >> 9;
  int et = rest % ET;
  int kk = rest / ET;
  int row = et * 16 + (lane & 15);
  int col = kk * 32 + ((lane >> 4) << 3) + i;
  pd.dst[seg][tid] = f2bf(pd.src[seg][(size_t)row * K + col]);
}

// Stage 1: LN(inputs) -> bf16, written PRE-SWIZZLED into kb (the buffer kv_kernel
// will read as its tile source and then overwrite with K). Pure streaming kernel.
__global__ __launch_bounds__(256, 4) void ln_kernel(
    const float* __restrict__ inp, const float* __restrict__ g, const float* __restrict__ bta,
    unsigned short* __restrict__ xln)
{
  const int t = threadIdx.x, w = t >> 6, l = t & 63;
  const size_t row0 = (size_t)blockIdx.x * 64;
  const int li = l & 15, lg = l >> 4;

  float4 gg[4], bb[4];
  #pragma unroll
  for(int q = 0; q < 4; ++q){
    gg[q] = ((const float4*)g)[li + q * 16];
    bb[q] = ((const float4*)bta)[li + q * 16];
  }
  #pragma unroll
  for(int rr = 0; rr < 4; ++rr){
    int r = w * 16 + rr * 4 + lg;
    const float4* rp = (const float4*)(inp + (row0 + r) * DD);
    float4 x[4];
    #pragma unroll
    for(int q = 0; q < 4; ++q) x[q] = rp[li + q * 16];
    float s1 = 0.f, s2 = 0.f;
    #pragma unroll
    for(int q = 0; q < 4; ++q){
      s1 += x[q].x + x[q].y + x[q].z + x[q].w;
      s2 += x[q].x*x[q].x + x[q].y*x[q].y + x[q].z*x[q].z + x[q].w*x[q].w;
    }
    #pragma unroll
    for(int o = 8; o >= 1; o >>= 1){ s1 += __shfl_xor(s1, o); s2 += __shfl_xor(s2, o); }
    float mean = s1 * (1.0f/256.0f);
    float inv  = rsqrtf(s2 * (1.0f/256.0f) - mean*mean + 1e-5f);
    #pragma unroll
    for(int q = 0; q < 4; ++q){
      float y0 = (x[q].x-mean)*inv*gg[q].x + bb[q].x;
      float y1 = (x[q].y-mean)*inv*gg[q].y + bb[q].y;
      float y2 = (x[q].z-mean)*inv*gg[q].z + bb[q].z;
      float y3 = (x[q].w-mean)*inv*gg[q].w + bb[q].w;
      size_t byte = (row0 + r) * 512 + ((q * 128 + li * 8) ^ ((r & 7) << 4));
      *(uint2*)((char*)xln + byte) = make_uint2(pk2(y0,y1), pk2(y2,y3));
    }
  }
}

// Stage 2: tile of pre-swizzled x -> LDS via global_load_lds (identity copy),
// then K = x@Wk^T (row-major, overwrites the same kb rows) and V^T = (x@Wv^T)^T.
__global__ __launch_bounds__(256, 2) void kv_kernel(
    unsigned short* kb,                      // in: swizzled x ; out: K row-major
    const short8* __restrict__ wkp, const short8* __restrict__ wvp,
    unsigned short* __restrict__ vT)
{
  __shared__ unsigned short xs[64 * 256];      // 32 KB tile (swizzled layout)
  __shared__ unsigned short vstage[4][1024];   // 8 KB per-warp V^T staging
  const int t = threadIdx.x, w = t >> 6, l = t & 63;
  const size_t row0 = (size_t)blockIdx.x * 64;
  const int b = (int)(row0 >> 12);
  const int n_base = (int)(row0 & 4095);
  const int li = l & 15, lg = l >> 4;

  // DMA the 32 KB tile: 8 x 1KB per warp, LDS base wave-uniform, global per-lane.
  {
    const char* gsrc = (const char*)kb + row0 * 512;
    #pragma unroll
    for(int i = 0; i < 8; ++i){
      int off = w * 8192 + i * 1024;
      gl_lds16(gsrc + off + l * 16, (char*)xs + off);
    }
  }
  asm volatile("s_waitcnt vmcnt(0)" ::: "memory");
  __syncthreads();

  const int et0 = w * 4;
  // K: swapped operands => lane holds 4 consecutive d at fixed n; direct 8B stores.
  #pragma unroll
  for(int el = 0; el < 4; ++el){
    const int et = et0 + el;
    short8 wb[8];
    #pragma unroll
    for(int kk = 0; kk < 8; ++kk) wb[kk] = wkp[((kk * 16 + et) << 6) + l];
    #pragma unroll
    for(int rg = 0; rg < 4; ++rg){
      const int r = rg * 16 + li;
      f32x4 a = (f32x4){0,0,0,0};
      #pragma unroll
      for(int kk = 0; kk < 8; ++kk){
        int ab = r * 512 + (((kk * 64) + (lg << 4)) ^ ((r & 7) << 4));
        short8 afr = *(const short8*)((const char*)xs + ab);
        a = MFMA(wb[kk], afr, a);
      }
      size_t row = row0 + rg * 16 + li;
      int colb = et * 16 + (lg << 2);
      *(uint2*)(kb + row * DD + colb) = make_uint2(pk2(a[0],a[1]), pk2(a[2],a[3]));
    }
  }
  // V: direct operands; stage per-warp in LDS; coalesced 16B stores of V^T rows.
  #pragma unroll
  for(int el = 0; el < 4; ++el){
    const int et = et0 + el;
    short8 wb[8];
    #pragma unroll
    for(int kk = 0; kk < 8; ++kk) wb[kk] = wvp[((kk * 16 + et) << 6) + l];
    char* vs = (char*)&vstage[w][0];
    #pragma unroll
    for(int rg = 0; rg < 4; ++rg){
      const int r = rg * 16 + li;
      f32x4 a = (f32x4){0,0,0,0};
      #pragma unroll
      for(int kk = 0; kk < 8; ++kk){
        int ab = r * 512 + (((kk * 64) + (lg << 4)) ^ ((r & 7) << 4));
        short8 afr = *(const short8*)((const char*)xs + ab);
        a = MFMA(afr, wb[kk], a);
      }
      int nloc = rg * 16 + (lg << 2);
      int byte = li * 128 + ((nloc * 2) ^ ((li & 7) << 4));
      *(uint2*)(vs + byte) = make_uint2(pk2(a[0],a[1]), pk2(a[2],a[3]));
    }
    asm volatile("s_waitcnt lgkmcnt(0)" ::: "memory");
    #pragma unroll
    for(int u = 0; u < 2; ++u){
      int dl = u * 8 + (l >> 3);
      int byte = dl * 128 + (((l & 7) * 16) ^ ((dl & 7) << 4));
      uint4 vv = *(uint4*)(vs + byte);
      int d = et * 16 + dl;
      *(uint4*)(vT + ((size_t)(b * 256 + d) << 12) + n_base + (l & 7) * 8) = vv;
    }
    asm volatile("" ::: "memory");
  }
}

// slots0 = mu + exp(log_sigma)*noise ; q = LN_slots(slots0)@Wq^T * D^-0.5
__global__ __launch_bounds__(256, 1) void init_kernel(
    const float* __restrict__ noise, const float* __restrict__ mu, const float* __restrict__ lsg,
    const float* __restrict__ lng, const float* __restrict__ lnb,
    const short8* __restrict__ wqp, float* __restrict__ slots, float* __restrict__ qbuf)
{
  const int b = blockIdx.x, t = threadIdx.x, w = t >> 6, l = t & 63;
  __shared__ float SLN[SS * DD];
  __shared__ unsigned short A1[16 * DD];
  float muv = mu[t];
  float sgv = __expf(lsg[t]);
  #pragma unroll
  for(int s = 0; s < SS; ++s){
    float v = muv + sgv * noise[(size_t)b * 2048 + s * 256 + t];
    slots[(size_t)b * 2048 + s * 256 + t] = v;
    SLN[s * 256 + t] = v;
  }
  __syncthreads();
  float4 g4 = ((const float4*)lng)[l], bb4 = ((const float4*)lnb)[l];
  for(int sh = 0; sh < 2; ++sh){
    int s = w * 2 + sh;
    float4 x4 = ((const float4*)(SLN + s * 256))[l];
    float s1 = x4.x + x4.y + x4.z + x4.w;
    float s2 = x4.x*x4.x + x4.y*x4.y + x4.z*x4.z + x4.w*x4.w;
    #pragma unroll
    for(int o = 32; o >= 1; o >>= 1){ s1 += __shfl_xor(s1, o); s2 += __shfl_xor(s2, o); }
    float mean = s1 * (1.0f/256.0f);
    float inv  = rsqrtf(s2 * (1.0f/256.0f) - mean*mean + 1e-5f);
    float y0 = (x4.x-mean)*inv*g4.x + bb4.x;
    float y1 = (x4.y-mean)*inv*g4.y + bb4.y;
    float y2 = (x4.z-mean)*inv*g4.z + bb4.z;
    float y3 = (x4.w-mean)*inv*g4.w + bb4.w;
    int byte = s * 512 + ((l * 8) ^ ((s & 7) << 4));
    *(uint2*)((char*)A1 + byte) = make_uint2(pk2(y0,y1), pk2(y2,y3));
  }
  __syncthreads();
  const int m = l & 15;
  short8 af[8];
  #pragma unroll
  for(int kk = 0; kk < 8; ++kk){
    int ab = m * 512 + (((kk * 64) + ((l >> 4) << 4)) ^ ((m & 7) << 4));
    af[kk] = *(const short8*)((const char*)A1 + ab);
  }
  #pragma unroll
  for(int i = 0; i < 4; ++i){
    int et = w + i * 4;
    f32x4 c = (f32x4){0,0,0,0};
    #pragma unroll
    for(int kk = 0; kk < 8; ++kk) c = MFMA(af[kk], wqp[((kk * 16 + et) << 6) + l], c);
    int e = et * 16 + (l & 15);
    #pragma unroll
    for(int j = 0; j < 4; ++j){
      int s = ((l >> 4) << 2) + j;
      if(s < 8) qbuf[(size_t)b * 2048 + s * 256 + e] = c[j] * 0.0625f;
    }
  }
}

// MFMA flash-attention partials: QK^T (A=q from qbuf, B=K row-major), softmax, P@V (A=P, B=V^T).
__global__ __launch_bounds__(256, 3) void attn_kernel(
    const unsigned short* __restrict__ kb_, const unsigned short* __restrict__ vT_,
    const float* __restrict__ qbuf, float* __restrict__ pupd, float* __restrict__ pms)
{
  const int blk = blockIdx.x;
  const int b = blk >> 3, c = blk & 7;
  const int t = threadIdx.x, w = t >> 6, l = t & 63;
  __shared__ float ls[8 * LSP];   // 16.5 KB: exp(logits) rows 0..7

  const int m = l & 15;
  short8 aq[8];
  #pragma unroll
  for(int kk = 0; kk < 8; ++kk){
    if(m < 8){
      const float* qp = qbuf + (size_t)b * 2048 + m * 256 + kk * 32 + ((l >> 4) << 3);
      float4 qa = *(const float4*)qp;
      float4 qb = *(const float4*)(qp + 4);
      int4 pv = make_int4((int)pk2(qa.x,qa.y), (int)pk2(qa.z,qa.w),
                          (int)pk2(qb.x,qb.y), (int)pk2(qb.z,qb.w));
      aq[kk] = __builtin_bit_cast(short8, pv);
    } else {
      aq[kk] = (short8){0,0,0,0,0,0,0,0};
    }
  }

  const unsigned short* kb = kb_ + ((size_t)b * NN + (size_t)c * CHK) * DD;
  #pragma unroll
  for(int nt = 0; nt < 8; ++nt){
    int nb = w * 128 + nt * 16;
    f32x4 acc = (f32x4){0,0,0,0};
    #pragma unroll
    for(int kk = 0; kk < 8; ++kk){
      short8 bk = *(const short8*)(kb + (size_t)(nb + m) * DD + kk * 32 + ((l >> 4) << 3));
      acc = MFMA(aq[kk], bk, acc);
    }
    if(l < 32){
      int s4 = (l >> 4) * 4;
      #pragma unroll
      for(int j = 0; j < 4; ++j) ls[(s4 + j) * LSP + nb + m] = acc[j];
    }
  }
  __syncthreads();

  for(int sh = 0; sh < 2; ++sh){
    int s = w * 2 + sh;
    float* base = ls + s * LSP;
    float4 v0 = *(float4*)(base + l * 4);
    float4 v1 = *(float4*)(base + 256 + l * 4);
    float mx = fmaxf(fmaxf(fmaxf(v0.x,v0.y),fmaxf(v0.z,v0.w)),
                     fmaxf(fmaxf(v1.x,v1.y),fmaxf(v1.z,v1.w)));
    #pragma unroll
    for(int o = 32; o >= 1; o >>= 1) mx = fmaxf(mx, __shfl_xor(mx, o));
    float e0 = __expf(v0.x-mx), e1 = __expf(v0.y-mx), e2 = __expf(v0.z-mx), e3 = __expf(v0.w-mx);
    float e4 = __expf(v1.x-mx), e5 = __expf(v1.y-mx), e6 = __expf(v1.z-mx), e7 = __expf(v1.w-mx);
    float sm = e0+e1+e2+e3+e4+e5+e6+e7;
    #pragma unroll
    for(int o = 32; o >= 1; o >>= 1) sm += __shfl_xor(sm, o);
    *(float4*)(base + l * 4)       = make_float4(e0,e1,e2,e3);
    *(float4*)(base + 256 + l * 4) = make_float4(e4,e5,e6,e7);
    if(l == 0){
      pms[(((size_t)b * 8 + c) * 8 + s) * 2    ] = mx;
      pms[(((size_t)b * 8 + c) * 8 + s) * 2 + 1] = sm;
    }
  }
  __syncthreads();

  short8 pa[16];
  #pragma unroll
  for(int kk = 0; kk < 16; ++kk){
    if(m < 8){
      const float* pp = ls + m * LSP + kk * 32 + ((l >> 4) << 3);
      int4 pv = make_int4((int)pk2(pp[0],pp[1]), (int)pk2(pp[2],pp[3]),
                          (int)pk2(pp[4],pp[5]), (int)pk2(pp[6],pp[7]));
      pa[kk] = __builtin_bit_cast(short8, pv);
    } else {
      pa[kk] = (short8){0,0,0,0,0,0,0,0};
    }
  }

  const unsigned short* vt = vT_ + ((size_t)b << 20) + (size_t)c * CHK;
  #pragma unroll
  for(int dt = 0; dt < 4; ++dt){
    int d0 = w * 64 + dt * 16;
    f32x4 acc = (f32x4){0,0,0,0};
    #pragma unroll
    for(int kk = 0; kk < 16; ++kk){
      short8 bv = *(const short8*)(vt + ((size_t)(d0 + m) << 12) + kk * 32 + ((l >> 4) << 3));
      acc = MFMA(pa[kk], bv, acc);
    }
    if(l < 32){
      int s4 = (l >> 4) * 4;
      #pragma unroll
      for(int j = 0; j < 4; ++j)
        pupd[((size_t)b * 8 + c) * 2048 + (s4 + j) * 256 + d0 + m] = acc[j];
    }
  }
}

// Combine partials -> upd ; GRU ; residual MLP ; write slots (+dout) ; LN_slots ; next q
// 1024 threads / 16 warps: halves every serial MFMA chain vs the 512-thread version.
__global__ __launch_bounds__(1024, 1) void update_kernel(
    const float* __restrict__ pupd, const float* __restrict__ pms,
    float* __restrict__ slots, float* __restrict__ qbuf,
    const short8* __restrict__ wih, const short8* __restrict__ whh,
    const float* __restrict__ bih, const float* __restrict__ bhh,
    const short8* __restrict__ w1p, const float* __restrict__ b1v,
    const short8* __restrict__ w2p, const float* __restrict__ b2v,
    const float* __restrict__ lnsg, const float* __restrict__ lnsb,
    const float* __restrict__ lnmg, const float* __restrict__ lnmb,
    const short8* __restrict__ wqp,
    float* __restrict__ dout, const int last)
{
  const int b = blockIdx.x, t = threadIdx.x, w = t >> 6, l = t & 63;
  __shared__ unsigned short A1[16 * 256];
  __shared__ unsigned short A2[16 * 256];
  __shared__ unsigned short A3[16 * 512];
  __shared__ float GR[8 * 256], GZ[8 * 256], GXN[8 * 256], GHN[8 * 256];
  __shared__ float SL[8 * 256];
  __shared__ float PMS[128];

  if(t < 128) PMS[t] = pms[(size_t)b * 128 + t];
  __syncthreads();

  const int col = t & 255, sg = t >> 8;  // sg in {0..3}; this thread owns slots sg*2, sg*2+1
  float upd[2], pv[2];
  #pragma unroll
  for(int ss = 0; ss < 2; ++ss){
    int s = sg * 2 + ss;
    float mx = -1e30f;
    #pragma unroll
    for(int cc = 0; cc < 8; ++cc) mx = fmaxf(mx, PMS[(cc * 8 + s) * 2]);
    float Z = 0.f, u = 0.f;
    #pragma unroll
    for(int cc = 0; cc < 8; ++cc){
      float e = __expf(PMS[(cc * 8 + s) * 2] - mx);
      Z += e * PMS[(cc * 8 + s) * 2 + 1];
      u += e * pupd[((size_t)b * 8 + cc) * 2048 + s * 256 + col];
    }
    upd[ss] = u / Z;
    pv[ss]  = slots[(size_t)b * 2048 + s * 256 + col];
  }
  #pragma unroll
  for(int ss = 0; ss < 2; ++ss){
    int s = sg * 2 + ss;
    int byte = s * 512 + ((col * 2) ^ ((s & 7) << 4));
    *(unsigned short*)((char*)A1 + byte) = f2bf(upd[ss]);
    *(unsigned short*)((char*)A2 + byte) = f2bf(pv[ss]);
  }
  __syncthreads();

  {
    const int m = l & 15;
    short8 a1f[8], a2f[8];
    #pragma unroll
    for(int kk = 0; kk < 8; ++kk){
      int ab = m * 512 + (((kk * 64) + ((l >> 4) << 4)) ^ ((m & 7) << 4));
      a1f[kk] = *(const short8*)((const char*)A1 + ab);
      a2f[kk] = *(const short8*)((const char*)A2 + ab);
    }
    #pragma unroll
    for(int i = 0; i < 3; ++i){
      int et = w + i * 16;
      f32x4 c1 = (f32x4){0,0,0,0}, c2 = (f32x4){0,0,0,0};
      #pragma unroll
      for(int kk = 0; kk < 8; ++kk){
        c1 = MFMA(a1f[kk], wih[((kk * 48 + et) << 6) + l], c1);
        c2 = MFMA(a2f[kk], whh[((kk * 48 + et) << 6) + l], c2);
      }
      int e = et * 16 + (l & 15);
      float xb = bih[e], hb = bhh[e];
      #pragma unroll
      for(int j = 0; j < 4; ++j){
        int s = ((l >> 4) << 2) + j;
        if(s < 8){
          float x = c1[j] + xb, h = c2[j] + hb;
          if(i == 0)      GR[s * 256 + e      ] = 1.f/(1.f + __expf(-(x + h)));
          else if(i == 1) GZ[s * 256 + (e-256)] = 1.f/(1.f + __expf(-(x + h)));
          else { GXN[s * 256 + (e-512)] = x; GHN[s * 256 + (e-512)] = h; }
        }
      }
    }
  }
  __syncthreads();

  #pragma unroll
  for(int ss = 0; ss < 2; ++ss){
    int s = sg * 2 + ss, idx = s * 256 + col;
    float r = GR[idx], z = GZ[idx], xn = GXN[idx], hn = GHN[idx];
    float nn = tanhf(xn + r * hn);
    SL[idx] = (1.f - z) * nn + z * pv[ss];
  }
  __syncthreads();

  if(w < 8){
    float4 g4 = ((const float4*)lnmg)[l], bb4 = ((const float4*)lnmb)[l];
    int s = w;
    float4 x4 = ((const float4*)(SL + s * 256))[l];
    float s1 = x4.x + x4.y + x4.z + x4.w;
    float s2 = x4.x*x4.x + x4.y*x4.y + x4.z*x4.z + x4.w*x4.w;
    #pragma unroll
    for(int o = 32; o >= 1; o >>= 1){ s1 += __shfl_xor(s1, o); s2 += __shfl_xor(s2, o); }
    float mean = s1 * (1.0f/256.0f);
    float inv  = rsqrtf(s2 * (1.0f/256.0f) - mean*mean + 1e-5f);
    float y0 = (x4.x-mean)*inv*g4.x + bb4.x;
    float y1 = (x4.y-mean)*inv*g4.y + bb4.y;
    float y2 = (x4.z-mean)*inv*g4.z + bb4.z;
    float y3 = (x4.w-mean)*inv*g4.w + bb4.w;
    int byte = s * 512 + ((l * 8) ^ ((s & 7) << 4));
    *(uint2*)((char*)A1 + byte) = make_uint2(pk2(y0,y1), pk2(y2,y3));
  }
  __syncthreads();

  {
    const int m = l & 15;
    short8 af[8];
    #pragma unroll
    for(int kk = 0; kk < 8; ++kk){
      int ab = m * 512 + (((kk * 64) + ((l >> 4) << 4)) ^ ((m & 7) << 4));
      af[kk] = *(const short8*)((const char*)A1 + ab);
    }
    #pragma unroll
    for(int i = 0; i < 2; ++i){
      int et = w + i * 16;
      f32x4 c = (f32x4){0,0,0,0};
      #pragma unroll
      for(int kk = 0; kk < 8; ++kk) c = MFMA(af[kk], w1p[((kk * 32 + et) << 6) + l], c);
      int e = et * 16 + (l & 15);
      float bb = b1v[e];
      #pragma unroll
      for(int j = 0; j < 4; ++j){
        int s = ((l >> 4) << 2) + j;
        if(s < 8){
          float h = fmaxf(c[j] + bb, 0.f);
          int byte = s * 1024 + ((e * 2) ^ ((s & 7) << 4));
          *(unsigned short*)((char*)A3 + byte) = f2bf(h);
        }
      }
    }
  }
  __syncthreads();

  {
    const int m = l & 15;
    short8 af[16];
    #pragma unroll
    for(int kk = 0; kk < 16; ++kk){
      int ab = m * 1024 + (((kk * 64) + ((l >> 4) << 4)) ^ ((m & 7) << 4));
      af[kk] = *(const short8*)((const char*)A3 + ab);
    }
    {
      int et = w;
      f32x4 c = (f32x4){0,0,0,0};
      #pragma unroll
      for(int kk = 0; kk < 16; ++kk) c = MFMA(af[kk], w2p[((kk * 16 + et) << 6) + l], c);
      int e = et * 16 + (l & 15);
      float bb = b2v[e];
      #pragma unroll
      for(int j = 0; j < 4; ++j){
        int s = ((l >> 4) << 2) + j;
        if(s < 8) GR[s * 256 + e] = SL[s * 256 + e] + c[j] + bb;
      }
    }
  }
  __syncthreads();

  for(int i = t; i < 2048; i += 1024){
    float v = GR[i];
    slots[(size_t)b * 2048 + i] = v;
    if(last) dout[(size_t)b * 2048 + i] = v;
  }
  if(w < 8){
    float4 g4 = ((const float4*)lnsg)[l], bb4 = ((const float4*)lnsb)[l];
    int s = w;
    float4 x4 = ((const float4*)(GR + s * 256))[l];
    float s1 = x4.x + x4.y + x4.z + x4.w;
    float s2 = x4.x*x4.x + x4.y*x4.y + x4.z*x4.z + x4.w*x4.w;
    #pragma unroll
    for(int o = 32; o >= 1; o >>= 1){ s1 += __shfl_xor(s1, o); s2 += __shfl_xor(s2, o); }
    float mean = s1 * (1.0f/256.0f);
    float inv  = rsqrtf(s2 * (1.0f/256.0f) - mean*mean + 1e-5f);
    float y0 = (x4.x-mean)*inv*g4.x + bb4.x;
    float y1 = (x4.y-mean)*inv*g4.y + bb4.y;
    float y2 = (x4.z-mean)*inv*g4.z + bb4.z;
    float y3 = (x4.w-mean)*inv*g4.w + bb4.w;
    int byte = s * 512 + ((l * 8) ^ ((s & 7) << 4));
    *(uint2*)((char*)A1 + byte) = make_uint2(pk2(y0,y1), pk2(y2,y3));
  }
  __syncthreads();
  {
    const int m = l & 15;
    short8 af[8];
    #pragma unroll
    for(int kk = 0; kk < 8; ++kk){
      int ab = m * 512 + (((kk * 64) + ((l >> 4) << 4)) ^ ((m & 7) << 4));
      af[kk] = *(const short8*)((const char*)A1 + ab);
    }
    {
      int et = w;
      f32x4 c = (f32x4){0,0,0,0};
      #pragma unroll
      for(int kk = 0; kk < 8; ++kk) c = MFMA(af[kk], wqp[((kk * 16 + et) << 6) + l], c);
      int e = et * 16 + (l & 15);
      #pragma unroll
      for(int j = 0; j < 4; ++j){
        int s = ((l >> 4) << 2) + j;
        if(s < 8) qbuf[(size_t)b * 2048 + s * 256 + e] = c[j] * 0.0625f;
      }
    }
  }
}

extern "C" void kernel_launch(void* const* d_in, const int* in_sizes, int n_in,
                              void* d_out, int out_size, void* d_ws, size_t ws_size,
                              hipStream_t stream)
{
  const float* inp   = (const float*)d_in[0];
  const float* noise = (const float*)d_in[1];
  const float* mu    = (const float*)d_in[2];
  const float* lsg   = (const float*)d_in[3];
  const float* lngi  = (const float*)d_in[4];
  const float* lnbi  = (const float*)d_in[5];
  const float* lngs  = (const float*)d_in[6];
  const float* lnbs  = (const float*)d_in[7];
  const float* lngm  = (const float*)d_in[8];
  const float* lnbm  = (const float*)d_in[9];
  const float* Wq    = (const float*)d_in[10];
  const float* Wk    = (const float*)d_in[11];
  const float* Wv    = (const float*)d_in[12];
  const float* Wih   = (const float*)d_in[13];
  const float* Whh   = (const float*)d_in[14];
  const float* bih   = (const float*)d_in[15];
  const float* bhh   = (const float*)d_in[16];
  const float* W1    = (const float*)d_in[17];
  const float* b1    = (const float*)d_in[18];
  const float* W2    = (const float*)d_in[19];
  const float* b2    = (const float*)d_in[20];
  float* dout = (float*)d_out;

  char* ws = (char*)d_ws;
  size_t off = 0;
  unsigned short* kb  = (unsigned short*)(ws + off); off += (size_t)BB*NN*DD*2;
  unsigned short* vT  = (unsigned short*)(ws + off); off += (size_t)BB*NN*DD*2;
  short8* wqp = (short8*)(ws + off); off += (size_t)256*256*2;
  short8* wkp = (short8*)(ws + off); off += (size_t)256*256*2;
  short8* wvp = (short8*)(ws + off); off += (size_t)256*256*2;
  short8* wihp= (short8*)(ws + off); off += (size_t)768*256*2;
  short8* whhp= (short8*)(ws + off); off += (size_t)768*256*2;
  short8* w1p = (short8*)(ws + off); off += (size_t)512*256*2;
  short8* w2p = (short8*)(ws + off); off += (size_t)256*512*2;
  float* qbuf = (float*)(ws + off); off += (size_t)512*256*4;
  float* slots= (float*)(ws + off); off += (size_t)512*256*4;
  float* pupd = (float*)(ws + off); off += (size_t)64*8*8*256*4;
  float* pms  = (float*)(ws + off); off += (size_t)64*8*8*2*4;

  PackDesc pd;
  const float* srcs[7] = {Wq, Wk, Wv, Wih, Whh, W1, W2};
  unsigned short* dsts[7] = {(unsigned short*)wqp, (unsigned short*)wkp, (unsigned short*)wvp,
                             (unsigned short*)wihp, (unsigned short*)whhp,
                             (unsigned short*)w1p, (unsigned short*)w2p};
  int ets[7] = {16, 16, 16, 48, 48, 32, 16};
  int ks [7] = {256, 256, 256, 256, 256, 256, 512};
  int cum = 0;
  for(int i = 0; i < 7; ++i){
    pd.src[i] = srcs[i]; pd.dst[i] = dsts[i]; pd.ET[i] = ets[i]; pd.K[i] = ks[i];
    pd.blkStart[i] = cum;
    cum += (ets[i] * 16 * ks[i] + 255) / 256;
  }
  pd.blkStart[7] = cum;
  pack_all_kernel<<<cum, 256, 0, stream>>>(pd);

  ln_kernel<<<4096, 256, 0, stream>>>(inp, lngi, lnbi, kb);
  kv_kernel<<<4096, 256, 0, stream>>>(kb, wkp, wvp, vT);
  init_kernel<<<64, 256, 0, stream>>>(noise, mu, lsg, lngs, lnbs, wqp, slots, qbuf);

  for(int it = 0; it < 3; ++it){
    attn_kernel<<<512, 256, 0, stream>>>(kb, vT, qbuf, pupd, pms);
    update_kernel<<<64, 1024, 0, stream>>>(pupd, pms, slots, qbuf, wihp, whhp,
        bih, bhh, w1p, b1, w2p, b2, lngs, lnbs, lngm, lnbm, wqp, dout, (it == 2) ? 1 : 0);
  }
}

// Round 9
// 405.037 us; speedup vs baseline: 1.1986x; 1.1986x over previous
//
#include <hip/hip_runtime.h>

// Slot attention, MI355X. B=64,N=4096,S=8,D=256,H=512,ITERS=3.
// Algebraic restructure: K,V never materialized.
//   logits = (s_ln @ Wqk) @ x^T,  Wqk = scale * Wq^T @ Wk   (precomputed)
//   gx     = (P @ x)/Z @ M^T,     M   = W_ih @ Wv           (precomputed)
#define BB 64
#define NN 4096
#define SS 8
#define DD 256
#define HH 512
#define NCH 8
#define CHK 512
#define LSP 516   // padded row stride (f32) for logits LDS
#define XSTR 520  // padded byte stride for ln transpose tile (512+8)

typedef __attribute__((ext_vector_type(4))) float f32x4;
typedef __attribute__((ext_vector_type(8))) short short8;
typedef __attribute__((ext_vector_type(8))) __bf16 bf16x8;

static __device__ __forceinline__ f32x4 MFMA(short8 a, short8 b, f32x4 c){
  return __builtin_amdgcn_mfma_f32_16x16x32_bf16(
      __builtin_bit_cast(bf16x8, a), __builtin_bit_cast(bf16x8, b), c, 0, 0, 0);
}

static __device__ __forceinline__ unsigned short f2bf(float f){
  unsigned int x = __builtin_bit_cast(unsigned int, f);
  x += 0x7FFFu + ((x >> 16) & 1u);
  return (unsigned short)(x >> 16);
}

static __device__ __forceinline__ unsigned int pk2(float a, float b){
  return (unsigned int)f2bf(a) | ((unsigned int)f2bf(b) << 16);
}

// ---- precompute Wqk^T: out[d2][d1] = scale * sum_e Wq[e][d1]*Wk[e][d2]
__global__ __launch_bounds__(256, 4) void wqkT_kernel(
    const float* __restrict__ Wq, const float* __restrict__ Wk, float* __restrict__ out)
{
  __shared__ float sh[256];
  const int d2 = blockIdx.x, t = threadIdx.x;
  sh[t] = Wk[(size_t)t * 256 + d2];
  __syncthreads();
  float acc = 0.f;
  #pragma unroll 8
  for(int e = 0; e < 256; ++e) acc += sh[e] * Wq[(size_t)e * 256 + t];
  out[(size_t)d2 * 256 + t] = acc * 0.0625f;
}

// ---- precompute M: out[e][c] = sum_d Wih[e][d]*Wv[d][c]
__global__ __launch_bounds__(256, 4) void m_kernel(
    const float* __restrict__ Wih, const float* __restrict__ Wv, float* __restrict__ out)
{
  __shared__ float sh[256];
  const int e = blockIdx.x, t = threadIdx.x;
  sh[t] = Wih[(size_t)e * 256 + t];
  __syncthreads();
  float acc = 0.f;
  #pragma unroll 8
  for(int d = 0; d < 256; ++d) acc += sh[d] * Wv[(size_t)d * 256 + t];
  out[(size_t)e * 256 + t] = acc;
}

// ---- merged weight pack: W(E=ET*16, K) fp32 row-major -> bf16 MFMA fragments
struct PackDesc {
  const float* src[7];
  unsigned short* dst[7];
  int ET[7];
  int K[7];
  int blkStart[8];
};

__global__ void pack_all_kernel(PackDesc pd){
  int blk = blockIdx.x;
  int seg = 0;
  #pragma unroll
  for(int i = 1; i < 7; ++i) if(blk >= pd.blkStart[i]) seg = i;
  int tid = (blk - pd.blkStart[seg]) * 256 + threadIdx.x;
  int ET = pd.ET[seg], K = pd.K[seg];
  if(tid >= ET * 16 * K) return;
  int i    = tid & 7;
  int lane = (tid >> 3) & 63;
  int rest = tid >> 9;
  int et = rest % ET;
  int kk = rest / ET;
  int row = et * 16 + (lane & 15);
  int col = kk * 32 + ((lane >> 4) << 3) + i;
  pd.dst[seg][tid] = f2bf(pd.src[seg][(size_t)row * K + col]);
}

// LN(inputs) -> x (bf16 row-major) AND x^T [b][d][n] (LDS-transposed, coalesced out).
__global__ __launch_bounds__(256, 4) void ln_kernel(
    const float* __restrict__ inp, const float* __restrict__ g, const float* __restrict__ bta,
    unsigned short* __restrict__ x, unsigned short* __restrict__ xT)
{
  __shared__ char xs[64 * XSTR];   // 33280 B transpose tile
  const int t = threadIdx.x, w = t >> 6, l = t & 63;
  const size_t row0 = (size_t)blockIdx.x * 64;
  const int b = (int)(row0 >> 12);
  const int n_base = (int)(row0 & 4095);
  const int li = l & 15, lg = l >> 4;

  float4 gg[4], bb[4];
  #pragma unroll
  for(int q = 0; q < 4; ++q){
    gg[q] = ((const float4*)g)[li + q * 16];
    bb[q] = ((const float4*)bta)[li + q * 16];
  }
  #pragma unroll
  for(int rr = 0; rr < 4; ++rr){
    int r = w * 16 + rr * 4 + lg;
    const float4* rp = (const float4*)(inp + (row0 + r) * DD);
    float4 xv[4];
    #pragma unroll
    for(int q = 0; q < 4; ++q) xv[q] = rp[li + q * 16];
    float s1 = 0.f, s2 = 0.f;
    #pragma unroll
    for(int q = 0; q < 4; ++q){
      s1 += xv[q].x + xv[q].y + xv[q].z + xv[q].w;
      s2 += xv[q].x*xv[q].x + xv[q].y*xv[q].y + xv[q].z*xv[q].z + xv[q].w*xv[q].w;
    }
    #pragma unroll
    for(int o = 8; o >= 1; o >>= 1){ s1 += __shfl_xor(s1, o); s2 += __shfl_xor(s2, o); }
    float mean = s1 * (1.0f/256.0f);
    float inv  = rsqrtf(s2 * (1.0f/256.0f) - mean*mean + 1e-5f);
    #pragma unroll
    for(int q = 0; q < 4; ++q){
      float y0 = (xv[q].x-mean)*inv*gg[q].x + bb[q].x;
      float y1 = (xv[q].y-mean)*inv*gg[q].y + bb[q].y;
      float y2 = (xv[q].z-mean)*inv*gg[q].z + bb[q].z;
      float y3 = (xv[q].w-mean)*inv*gg[q].w + bb[q].w;
      uint2 pv = make_uint2(pk2(y0,y1), pk2(y2,y3));
      // global x row-major
      *(uint2*)((char*)x + (row0 + r) * 512 + q * 128 + li * 8) = pv;
      // LDS transpose tile (swizzled)
      *(uint2*)(xs + r * XSTR + ((q * 128 + li * 8) ^ ((r & 7) << 4))) = pv;
    }
  }
  __syncthreads();

  // x^T out: thread handles (d = p*32 + t>>3, n = (t&7)*8 .. +7), 16B coalesced stores.
  const int dl = t >> 3, nv = t & 7;
  #pragma unroll
  for(int p = 0; p < 8; ++p){
    int d = p * 32 + dl;
    unsigned int u[4];
    #pragma unroll
    for(int jj = 0; jj < 4; ++jj){
      int n0 = nv * 8 + jj * 2;
      unsigned int lo = *(unsigned short*)(xs + n0 * XSTR + ((d * 2) ^ ((n0 & 7) << 4)));
      int n1 = n0 + 1;
      unsigned int hi = *(unsigned short*)(xs + n1 * XSTR + ((d * 2) ^ ((n1 & 7) << 4)));
      u[jj] = lo | (hi << 16);
    }
    uint4 vv = make_uint4(u[0], u[1], u[2], u[3]);
    *(uint4*)(xT + (((size_t)(b * 256 + d)) << 12) + n_base + nv * 8) = vv;
  }
}

// slots0 = mu + exp(log_sigma)*noise ; qk = LN_slots(slots0) @ Wqk  (scale folded)
__global__ __launch_bounds__(256, 1) void init_kernel(
    const float* __restrict__ noise, const float* __restrict__ mu, const float* __restrict__ lsg,
    const float* __restrict__ lng, const float* __restrict__ lnb,
    const short8* __restrict__ wqkp, float* __restrict__ slots, float* __restrict__ qbuf)
{
  const int b = blockIdx.x, t = threadIdx.x, w = t >> 6, l = t & 63;
  __shared__ float SLN[SS * DD];
  __shared__ unsigned short A1[16 * DD];
  float muv = mu[t];
  float sgv = __expf(lsg[t]);
  #pragma unroll
  for(int s = 0; s < SS; ++s){
    float v = muv + sgv * noise[(size_t)b * 2048 + s * 256 + t];
    slots[(size_t)b * 2048 + s * 256 + t] = v;
    SLN[s * 256 + t] = v;
  }
  __syncthreads();
  float4 g4 = ((const float4*)lng)[l], bb4 = ((const float4*)lnb)[l];
  for(int sh = 0; sh < 2; ++sh){
    int s = w * 2 + sh;
    float4 x4 = ((const float4*)(SLN + s * 256))[l];
    float s1 = x4.x + x4.y + x4.z + x4.w;
    float s2 = x4.x*x4.x + x4.y*x4.y + x4.z*x4.z + x4.w*x4.w;
    #pragma unroll
    for(int o = 32; o >= 1; o >>= 1){ s1 += __shfl_xor(s1, o); s2 += __shfl_xor(s2, o); }
    float mean = s1 * (1.0f/256.0f);
    float inv  = rsqrtf(s2 * (1.0f/256.0f) - mean*mean + 1e-5f);
    float y0 = (x4.x-mean)*inv*g4.x + bb4.x;
    float y1 = (x4.y-mean)*inv*g4.y + bb4.y;
    float y2 = (x4.z-mean)*inv*g4.z + bb4.z;
    float y3 = (x4.w-mean)*inv*g4.w + bb4.w;
    int byte = s * 512 + ((l * 8) ^ ((s & 7) << 4));
    *(uint2*)((char*)A1 + byte) = make_uint2(pk2(y0,y1), pk2(y2,y3));
  }
  __syncthreads();
  const int m = l & 15;
  short8 af[8];
  #pragma unroll
  for(int kk = 0; kk < 8; ++kk){
    int ab = m * 512 + (((kk * 64) + ((l >> 4) << 4)) ^ ((m & 7) << 4));
    af[kk] = *(const short8*)((const char*)A1 + ab);
  }
  #pragma unroll
  for(int i = 0; i < 4; ++i){
    int et = w + i * 4;
    f32x4 c = (f32x4){0,0,0,0};
    #pragma unroll
    for(int kk = 0; kk < 8; ++kk) c = MFMA(af[kk], wqkp[((kk * 16 + et) << 6) + l], c);
    int e = et * 16 + (l & 15);
    #pragma unroll
    for(int j = 0; j < 4; ++j){
      int s = ((l >> 4) << 2) + j;
      if(s < 8) qbuf[(size_t)b * 2048 + s * 256 + e] = c[j];
    }
  }
}

// MFMA flash partials: logits = qk@x^T (B=x row-major), softmax, PX = P@x (B=x^T).
__global__ __launch_bounds__(256, 3) void attn_kernel(
    const unsigned short* __restrict__ x_, const unsigned short* __restrict__ xT_,
    const float* __restrict__ qbuf, float* __restrict__ pupd, float* __restrict__ pms)
{
  const int blk = blockIdx.x;
  const int b = blk >> 3, c = blk & 7;
  const int t = threadIdx.x, w = t >> 6, l = t & 63;
  __shared__ float ls[8 * LSP];   // 16.5 KB: exp(logits) rows 0..7

  const int m = l & 15;
  short8 aq[8];
  #pragma unroll
  for(int kk = 0; kk < 8; ++kk){
    if(m < 8){
      const float* qp = qbuf + (size_t)b * 2048 + m * 256 + kk * 32 + ((l >> 4) << 3);
      float4 qa = *(const float4*)qp;
      float4 qb = *(const float4*)(qp + 4);
      int4 pv = make_int4((int)pk2(qa.x,qa.y), (int)pk2(qa.z,qa.w),
                          (int)pk2(qb.x,qb.y), (int)pk2(qb.z,qb.w));
      aq[kk] = __builtin_bit_cast(short8, pv);
    } else {
      aq[kk] = (short8){0,0,0,0,0,0,0,0};
    }
  }

  const unsigned short* xb = x_ + ((size_t)b * NN + (size_t)c * CHK) * DD;
  #pragma unroll
  for(int nt = 0; nt < 8; ++nt){
    int nb = w * 128 + nt * 16;
    f32x4 acc = (f32x4){0,0,0,0};
    #pragma unroll
    for(int kk = 0; kk < 8; ++kk){
      short8 bk = *(const short8*)(xb + (size_t)(nb + m) * DD + kk * 32 + ((l >> 4) << 3));
      acc = MFMA(aq[kk], bk, acc);
    }
    if(l < 32){
      int s4 = (l >> 4) * 4;
      #pragma unroll
      for(int j = 0; j < 4; ++j) ls[(s4 + j) * LSP + nb + m] = acc[j];
    }
  }
  __syncthreads();

  for(int sh = 0; sh < 2; ++sh){
    int s = w * 2 + sh;
    float* base = ls + s * LSP;
    float4 v0 = *(float4*)(base + l * 4);
    float4 v1 = *(float4*)(base + 256 + l * 4);
    float mx = fmaxf(fmaxf(fmaxf(v0.x,v0.y),fmaxf(v0.z,v0.w)),
                     fmaxf(fmaxf(v1.x,v1.y),fmaxf(v1.z,v1.w)));
    #pragma unroll
    for(int o = 32; o >= 1; o >>= 1) mx = fmaxf(mx, __shfl_xor(mx, o));
    float e0 = __expf(v0.x-mx), e1 = __expf(v0.y-mx), e2 = __expf(v0.z-mx), e3 = __expf(v0.w-mx);
    float e4 = __expf(v1.x-mx), e5 = __expf(v1.y-mx), e6 = __expf(v1.z-mx), e7 = __expf(v1.w-mx);
    float sm = e0+e1+e2+e3+e4+e5+e6+e7;
    #pragma unroll
    for(int o = 32; o >= 1; o >>= 1) sm += __shfl_xor(sm, o);
    *(float4*)(base + l * 4)       = make_float4(e0,e1,e2,e3);
    *(float4*)(base + 256 + l * 4) = make_float4(e4,e5,e6,e7);
    if(l == 0){
      pms[(((size_t)b * 8 + c) * 8 + s) * 2    ] = mx;
      pms[(((size_t)b * 8 + c) * 8 + s) * 2 + 1] = sm;
    }
  }
  __syncthreads();

  short8 pa[16];
  #pragma unroll
  for(int kk = 0; kk < 16; ++kk){
    if(m < 8){
      const float* pp = ls + m * LSP + kk * 32 + ((l >> 4) << 3);
      int4 pv = make_int4((int)pk2(pp[0],pp[1]), (int)pk2(pp[2],pp[3]),
                          (int)pk2(pp[4],pp[5]), (int)pk2(pp[6],pp[7]));
      pa[kk] = __builtin_bit_cast(short8, pv);
    } else {
      pa[kk] = (short8){0,0,0,0,0,0,0,0};
    }
  }

  const unsigned short* xt = xT_ + ((size_t)b << 20) + (size_t)c * CHK;
  #pragma unroll
  for(int dt = 0; dt < 4; ++dt){
    int d0 = w * 64 + dt * 16;
    f32x4 acc = (f32x4){0,0,0,0};
    #pragma unroll
    for(int kk = 0; kk < 16; ++kk){
      short8 bv = *(const short8*)(xt + ((size_t)(d0 + m) << 12) + kk * 32 + ((l >> 4) << 3));
      acc = MFMA(pa[kk], bv, acc);
    }
    if(l < 32){
      int s4 = (l >> 4) * 4;
      #pragma unroll
      for(int j = 0; j < 4; ++j)
        pupd[((size_t)b * 8 + c) * 2048 + (s4 + j) * 256 + d0 + m] = acc[j];
    }
  }
}

// Combine PX partials -> PX/Z ; GRU (gx = PXn@M^T) ; residual MLP ; slots ; LN ; next qk
__global__ __launch_bounds__(1024, 1) void update_kernel(
    const float* __restrict__ pupd, const float* __restrict__ pms,
    float* __restrict__ slots, float* __restrict__ qbuf,
    const short8* __restrict__ mp, const short8* __restrict__ whh,
    const float* __restrict__ bih, const float* __restrict__ bhh,
    const short8* __restrict__ w1p, const float* __restrict__ b1v,
    const short8* __restrict__ w2p, const float* __restrict__ b2v,
    const float* __restrict__ lnsg, const float* __restrict__ lnsb,
    const float* __restrict__ lnmg, const float* __restrict__ lnmb,
    const short8* __restrict__ wqkp,
    float* __restrict__ dout, const int last)
{
  const int b = blockIdx.x, t = threadIdx.x, w = t >> 6, l = t & 63;
  __shared__ unsigned short A1[16 * 256];
  __shared__ unsigned short A2[16 * 256];
  __shared__ unsigned short A3[16 * 512];
  __shared__ float GR[8 * 256], GZ[8 * 256], GXN[8 * 256], GHN[8 * 256];
  __shared__ float SL[8 * 256];
  __shared__ float PMS[128];

  if(t < 128) PMS[t] = pms[(size_t)b * 128 + t];
  __syncthreads();

  const int col = t & 255, sg = t >> 8;  // sg 0..3: slots sg*2, sg*2+1
  float upd[2], pv[2];
  #pragma unroll
  for(int ss = 0; ss < 2; ++ss){
    int s = sg * 2 + ss;
    float mx = -1e30f;
    #pragma unroll
    for(int cc = 0; cc < 8; ++cc) mx = fmaxf(mx, PMS[(cc * 8 + s) * 2]);
    float Z = 0.f, u = 0.f;
    #pragma unroll
    for(int cc = 0; cc < 8; ++cc){
      float e = __expf(PMS[(cc * 8 + s) * 2] - mx);
      Z += e * PMS[(cc * 8 + s) * 2 + 1];
      u += e * pupd[((size_t)b * 8 + cc) * 2048 + s * 256 + col];
    }
    upd[ss] = u / Z;
    pv[ss]  = slots[(size_t)b * 2048 + s * 256 + col];
  }
  #pragma unroll
  for(int ss = 0; ss < 2; ++ss){
    int s = sg * 2 + ss;
    int byte = s * 512 + ((col * 2) ^ ((s & 7) << 4));
    *(unsigned short*)((char*)A1 + byte) = f2bf(upd[ss]);
    *(unsigned short*)((char*)A2 + byte) = f2bf(pv[ss]);
  }
  __syncthreads();

  {
    const int m = l & 15;
    short8 a1f[8], a2f[8];
    #pragma unroll
    for(int kk = 0; kk < 8; ++kk){
      int ab = m * 512 + (((kk * 64) + ((l >> 4) << 4)) ^ ((m & 7) << 4));
      a1f[kk] = *(const short8*)((const char*)A1 + ab);
      a2f[kk] = *(const short8*)((const char*)A2 + ab);
    }
    #pragma unroll
    for(int i = 0; i < 3; ++i){
      int et = w + i * 16;
      f32x4 c1 = (f32x4){0,0,0,0}, c2 = (f32x4){0,0,0,0};
      #pragma unroll
      for(int kk = 0; kk < 8; ++kk){
        c1 = MFMA(a1f[kk], mp[((kk * 48 + et) << 6) + l], c1);
        c2 = MFMA(a2f[kk], whh[((kk * 48 + et) << 6) + l], c2);
      }
      int e = et * 16 + (l & 15);
      float xb = bih[e], hb = bhh[e];
      #pragma unroll
      for(int j = 0; j < 4; ++j){
        int s = ((l >> 4) << 2) + j;
        if(s < 8){
          float xx = c1[j] + xb, h = c2[j] + hb;
          if(i == 0)      GR[s * 256 + e      ] = 1.f/(1.f + __expf(-(xx + h)));
          else if(i == 1) GZ[s * 256 + (e-256)] = 1.f/(1.f + __expf(-(xx + h)));
          else { GXN[s * 256 + (e-512)] = xx; GHN[s * 256 + (e-512)] = h; }
        }
      }
    }
  }
  __syncthreads();

  #pragma unroll
  for(int ss = 0; ss < 2; ++ss){
    int s = sg * 2 + ss, idx = s * 256 + col;
    float r = GR[idx], z = GZ[idx], xn = GXN[idx], hn = GHN[idx];
    float nn = tanhf(xn + r * hn);
    SL[idx] = (1.f - z) * nn + z * pv[ss];
  }
  __syncthreads();

  if(w < 8){
    float4 g4 = ((const float4*)lnmg)[l], bb4 = ((const float4*)lnmb)[l];
    int s = w;
    float4 x4 = ((const float4*)(SL + s * 256))[l];
    float s1 = x4.x + x4.y + x4.z + x4.w;
    float s2 = x4.x*x4.x + x4.y*x4.y + x4.z*x4.z + x4.w*x4.w;
    #pragma unroll
    for(int o = 32; o >= 1; o >>= 1){ s1 += __shfl_xor(s1, o); s2 += __shfl_xor(s2, o); }
    float mean = s1 * (1.0f/256.0f);
    float inv  = rsqrtf(s2 * (1.0f/256.0f) - mean*mean + 1e-5f);
    float y0 = (x4.x-mean)*inv*g4.x + bb4.x;
    float y1 = (x4.y-mean)*inv*g4.y + bb4.y;
    float y2 = (x4.z-mean)*inv*g4.z + bb4.z;
    float y3 = (x4.w-mean)*inv*g4.w + bb4.w;
    int byte = s * 512 + ((l * 8) ^ ((s & 7) << 4));
    *(uint2*)((char*)A1 + byte) = make_uint2(pk2(y0,y1), pk2(y2,y3));
  }
  __syncthreads();

  {
    const int m = l & 15;
    short8 af[8];
    #pragma unroll
    for(int kk = 0; kk < 8; ++kk){
      int ab = m * 512 + (((kk * 64) + ((l >> 4) << 4)) ^ ((m & 7) << 4));
      af[kk] = *(const short8*)((const char*)A1 + ab);
    }
    #pragma unroll
    for(int i = 0; i < 2; ++i){
      int et = w + i * 16;
      f32x4 c = (f32x4){0,0,0,0};
      #pragma unroll
      for(int kk = 0; kk < 8; ++kk) c = MFMA(af[kk], w1p[((kk * 32 + et) << 6) + l], c);
      int e = et * 16 + (l & 15);
      float bb = b1v[e];
      #pragma unroll
      for(int j = 0; j < 4; ++j){
        int s = ((l >> 4) << 2) + j;
        if(s < 8){
          float h = fmaxf(c[j] + bb, 0.f);
          int byte = s * 1024 + ((e * 2) ^ ((s & 7) << 4));
          *(unsigned short*)((char*)A3 + byte) = f2bf(h);
        }
      }
    }
  }
  __syncthreads();

  {
    const int m = l & 15;
    short8 af[16];
    #pragma unroll
    for(int kk = 0; kk < 16; ++kk){
      int ab = m * 1024 + (((kk * 64) + ((l >> 4) << 4)) ^ ((m & 7) << 4));
      af[kk] = *(const short8*)((const char*)A3 + ab);
    }
    {
      int et = w;
      f32x4 c = (f32x4){0,0,0,0};
      #pragma unroll
      for(int kk = 0; kk < 16; ++kk) c = MFMA(af[kk], w2p[((kk * 16 + et) << 6) + l], c);
      int e = et * 16 + (l & 15);
      float bb = b2v[e];
      #pragma unroll
      for(int j = 0; j < 4; ++j){
        int s = ((l >> 4) << 2) + j;
        if(s < 8) GR[s * 256 + e] = SL[s * 256 + e] + c[j] + bb;
      }
    }
  }
  __syncthreads();

  for(int i = t; i < 2048; i += 1024){
    float v = GR[i];
    slots[(size_t)b * 2048 + i] = v;
    if(last) dout[(size_t)b * 2048 + i] = v;
  }
  if(w < 8){
    float4 g4 = ((const float4*)lnsg)[l], bb4 = ((const float4*)lnsb)[l];
    int s = w;
    float4 x4 = ((const float4*)(GR + s * 256))[l];
    float s1 = x4.x + x4.y + x4.z + x4.w;
    float s2 = x4.x*x4.x + x4.y*x4.y + x4.z*x4.z + x4.w*x4.w;
    #pragma unroll
    for(int o = 32; o >= 1; o >>= 1){ s1 += __shfl_xor(s1, o); s2 += __shfl_xor(s2, o); }
    float mean = s1 * (1.0f/256.0f);
    float inv  = rsqrtf(s2 * (1.0f/256.0f) - mean*mean + 1e-5f);
    float y0 = (x4.x-mean)*inv*g4.x + bb4.x;
    float y1 = (x4.y-mean)*inv*g4.y + bb4.y;
    float y2 = (x4.z-mean)*inv*g4.z + bb4.z;
    float y3 = (x4.w-mean)*inv*g4.w + bb4.w;
    int byte = s * 512 + ((l * 8) ^ ((s & 7) << 4));
    *(uint2*)((char*)A1 + byte) = make_uint2(pk2(y0,y1), pk2(y2,y3));
  }
  __syncthreads();
  {
    const int m = l & 15;
    short8 af[8];
    #pragma unroll
    for(int kk = 0; kk < 8; ++kk){
      int ab = m * 512 + (((kk * 64) + ((l >> 4) << 4)) ^ ((m & 7) << 4));
      af[kk] = *(const short8*)((const char*)A1 + ab);
    }
    {
      int et = w;
      f32x4 c = (f32x4){0,0,0,0};
      #pragma unroll
      for(int kk = 0; kk < 8; ++kk) c = MFMA(af[kk], wqkp[((kk * 16 + et) << 6) + l], c);
      int e = et * 16 + (l & 15);
      #pragma unroll
      for(int j = 0; j < 4; ++j){
        int s = ((l >> 4) << 2) + j;
        if(s < 8) qbuf[(size_t)b * 2048 + s * 256 + e] = c[j];
      }
    }
  }
}

extern "C" void kernel_launch(void* const* d_in, const int* in_sizes, int n_in,
                              void* d_out, int out_size, void* d_ws, size_t ws_size,
                              hipStream_t stream)
{
  const float* inp   = (const float*)d_in[0];
  const float* noise = (const float*)d_in[1];
  const float* mu    = (const float*)d_in[2];
  const float* lsg   = (const float*)d_in[3];
  const float* lngi  = (const float*)d_in[4];
  const float* lnbi  = (const float*)d_in[5];
  const float* lngs  = (const float*)d_in[6];
  const float* lnbs  = (const float*)d_in[7];
  const float* lngm  = (const float*)d_in[8];
  const float* lnbm  = (const float*)d_in[9];
  const float* Wq    = (const float*)d_in[10];
  const float* Wk    = (const float*)d_in[11];
  const float* Wv    = (const float*)d_in[12];
  const float* Wih   = (const float*)d_in[13];
  const float* Whh   = (const float*)d_in[14];
  const float* bih   = (const float*)d_in[15];
  const float* bhh   = (const float*)d_in[16];
  const float* W1    = (const float*)d_in[17];
  const float* b1    = (const float*)d_in[18];
  const float* W2    = (const float*)d_in[19];
  const float* b2    = (const float*)d_in[20];
  float* dout = (float*)d_out;

  char* ws = (char*)d_ws;
  size_t off = 0;
  unsigned short* x   = (unsigned short*)(ws + off); off += (size_t)BB*NN*DD*2;
  unsigned short* xT  = (unsigned short*)(ws + off); off += (size_t)BB*NN*DD*2;
  short8* wqkp= (short8*)(ws + off); off += (size_t)256*256*2;
  short8* mp  = (short8*)(ws + off); off += (size_t)768*256*2;
  short8* whhp= (short8*)(ws + off); off += (size_t)768*256*2;
  short8* w1p = (short8*)(ws + off); off += (size_t)512*256*2;
  short8* w2p = (short8*)(ws + off); off += (size_t)256*512*2;
  float* wqkT = (float*)(ws + off);  off += (size_t)256*256*4;
  float* mf32 = (float*)(ws + off);  off += (size_t)768*256*4;
  float* qbuf = (float*)(ws + off);  off += (size_t)512*256*4;
  float* slots= (float*)(ws + off);  off += (size_t)512*256*4;
  float* pupd = (float*)(ws + off);  off += (size_t)64*8*8*256*4;
  float* pms  = (float*)(ws + off);  off += (size_t)64*8*8*2*4;

  wqkT_kernel<<<256, 256, 0, stream>>>(Wq, Wk, wqkT);
  m_kernel<<<768, 256, 0, stream>>>(Wih, Wv, mf32);

  PackDesc pd;
  const float* srcs[7] = {wqkT, mf32, Whh, W1, W2, Wq, Wq};
  unsigned short* dsts[7] = {(unsigned short*)wqkp, (unsigned short*)mp,
                             (unsigned short*)whhp, (unsigned short*)w1p,
                             (unsigned short*)w2p, 0, 0};
  int ets[7] = {16, 48, 48, 32, 16, 0, 0};
  int ks [7] = {256, 256, 256, 256, 512, 0, 0};
  int cum = 0;
  for(int i = 0; i < 7; ++i){
    pd.src[i] = srcs[i]; pd.dst[i] = dsts[i]; pd.ET[i] = ets[i]; pd.K[i] = ks[i];
    pd.blkStart[i] = cum;
    cum += (ets[i] * 16 * ks[i] + 255) / 256;
  }
  pd.blkStart[7] = cum;
  pack_all_kernel<<<cum, 256, 0, stream>>>(pd);

  ln_kernel<<<4096, 256, 0, stream>>>(inp, lngi, lnbi, x, xT);
  init_kernel<<<64, 256, 0, stream>>>(noise, mu, lsg, lngs, lnbs, wqkp, slots, qbuf);

  for(int it = 0; it < 3; ++it){
    attn_kernel<<<512, 256, 0, stream>>>(x, xT, qbuf, pupd, pms);
    update_kernel<<<64, 1024, 0, stream>>>(pupd, pms, slots, qbuf, mp, whhp,
        bih, bhh, w1p, b1, w2p, b2, lngs, lnbs, lngm, lnbm, wqkp, dout, (it == 2) ? 1 : 0);
  }
}

// Round 10
// 366.268 us; speedup vs baseline: 1.3254x; 1.1058x over previous
//
#include <hip/hip_runtime.h>

// Slot attention, MI355X. B=64,N=4096,S=8,D=256,H=512,ITERS=3.
// K,V never materialized (Wqk = scale*Wq^T@Wk, M = W_ih@Wv folded).
// Single-copy x: PV re-reads the QK chunk via an LDS transpose (no xT buffer).
#define BB 64
#define NN 4096
#define SS 8
#define DD 256
#define HH 512
#define NCH 8
#define CHK 512
#define LSP 516   // padded row stride (f32) for logits LDS

typedef __attribute__((ext_vector_type(4))) float f32x4;
typedef __attribute__((ext_vector_type(8))) short short8;
typedef __attribute__((ext_vector_type(8))) __bf16 bf16x8;

static __device__ __forceinline__ f32x4 MFMA(short8 a, short8 b, f32x4 c){
  return __builtin_amdgcn_mfma_f32_16x16x32_bf16(
      __builtin_bit_cast(bf16x8, a), __builtin_bit_cast(bf16x8, b), c, 0, 0, 0);
}

static __device__ __forceinline__ unsigned short f2bf(float f){
  unsigned int x = __builtin_bit_cast(unsigned int, f);
  x += 0x7FFFu + ((x >> 16) & 1u);
  return (unsigned short)(x >> 16);
}

static __device__ __forceinline__ unsigned int pk2(float a, float b){
  return (unsigned int)f2bf(a) | ((unsigned int)f2bf(b) << 16);
}

// ---- precompute Wqk^T: out[d2][d1] = scale * sum_e Wq[e][d1]*Wk[e][d2]
__global__ __launch_bounds__(256, 4) void wqkT_kernel(
    const float* __restrict__ Wq, const float* __restrict__ Wk, float* __restrict__ out)
{
  __shared__ float sh[256];
  const int d2 = blockIdx.x, t = threadIdx.x;
  sh[t] = Wk[(size_t)t * 256 + d2];
  __syncthreads();
  float acc = 0.f;
  #pragma unroll 8
  for(int e = 0; e < 256; ++e) acc += sh[e] * Wq[(size_t)e * 256 + t];
  out[(size_t)d2 * 256 + t] = acc * 0.0625f;
}

// ---- precompute M: out[e][c] = sum_d Wih[e][d]*Wv[d][c]
__global__ __launch_bounds__(256, 4) void m_kernel(
    const float* __restrict__ Wih, const float* __restrict__ Wv, float* __restrict__ out)
{
  __shared__ float sh[256];
  const int e = blockIdx.x, t = threadIdx.x;
  sh[t] = Wih[(size_t)e * 256 + t];
  __syncthreads();
  float acc = 0.f;
  #pragma unroll 8
  for(int d = 0; d < 256; ++d) acc += sh[d] * Wv[(size_t)d * 256 + t];
  out[(size_t)e * 256 + t] = acc;
}

// ---- merged weight pack: W(E=ET*16, K) fp32 row-major -> bf16 MFMA fragments
struct PackDesc {
  const float* src[5];
  unsigned short* dst[5];
  int ET[5];
  int K[5];
  int blkStart[6];
};

__global__ void pack_all_kernel(PackDesc pd){
  int blk = blockIdx.x;
  int seg = 0;
  #pragma unroll
  for(int i = 1; i < 5; ++i) if(blk >= pd.blkStart[i]) seg = i;
  int tid = (blk - pd.blkStart[seg]) * 256 + threadIdx.x;
  int ET = pd.ET[seg], K = pd.K[seg];
  if(tid >= ET * 16 * K) return;
  int i    = tid & 7;
  int lane = (tid >> 3) & 63;
  int rest = tid >> 9;
  int et = rest % ET;
  int kk = rest / ET;
  int row = et * 16 + (lane & 15);
  int col = kk * 32 + ((lane >> 4) << 3) + i;
  pd.dst[seg][tid] = f2bf(pd.src[seg][(size_t)row * K + col]);
}

// LN(inputs) -> x (bf16 row-major). Pure streaming, no LDS.
__global__ __launch_bounds__(256, 4) void ln_kernel(
    const float* __restrict__ inp, const float* __restrict__ g, const float* __restrict__ bta,
    unsigned short* __restrict__ x)
{
  const int t = threadIdx.x, w = t >> 6, l = t & 63;
  const size_t row0 = (size_t)blockIdx.x * 64;
  const int li = l & 15, lg = l >> 4;

  float4 gg[4], bb[4];
  #pragma unroll
  for(int q = 0; q < 4; ++q){
    gg[q] = ((const float4*)g)[li + q * 16];
    bb[q] = ((const float4*)bta)[li + q * 16];
  }
  #pragma unroll
  for(int rr = 0; rr < 4; ++rr){
    int r = w * 16 + rr * 4 + lg;
    const float4* rp = (const float4*)(inp + (row0 + r) * DD);
    float4 xv[4];
    #pragma unroll
    for(int q = 0; q < 4; ++q) xv[q] = rp[li + q * 16];
    float s1 = 0.f, s2 = 0.f;
    #pragma unroll
    for(int q = 0; q < 4; ++q){
      s1 += xv[q].x + xv[q].y + xv[q].z + xv[q].w;
      s2 += xv[q].x*xv[q].x + xv[q].y*xv[q].y + xv[q].z*xv[q].z + xv[q].w*xv[q].w;
    }
    #pragma unroll
    for(int o = 8; o >= 1; o >>= 1){ s1 += __shfl_xor(s1, o); s2 += __shfl_xor(s2, o); }
    float mean = s1 * (1.0f/256.0f);
    float inv  = rsqrtf(s2 * (1.0f/256.0f) - mean*mean + 1e-5f);
    #pragma unroll
    for(int q = 0; q < 4; ++q){
      float y0 = (xv[q].x-mean)*inv*gg[q].x + bb[q].x;
      float y1 = (xv[q].y-mean)*inv*gg[q].y + bb[q].y;
      float y2 = (xv[q].z-mean)*inv*gg[q].z + bb[q].z;
      float y3 = (xv[q].w-mean)*inv*gg[q].w + bb[q].w;
      *(uint2*)((char*)x + (row0 + r) * 512 + q * 128 + li * 8) =
          make_uint2(pk2(y0,y1), pk2(y2,y3));
    }
  }
}

// slots0 = mu + exp(log_sigma)*noise ; qk = LN_slots(slots0) @ Wqk
__global__ __launch_bounds__(256, 1) void init_kernel(
    const float* __restrict__ noise, const float* __restrict__ mu, const float* __restrict__ lsg,
    const float* __restrict__ lng, const float* __restrict__ lnb,
    const short8* __restrict__ wqkp, float* __restrict__ slots, float* __restrict__ qbuf)
{
  const int b = blockIdx.x, t = threadIdx.x, w = t >> 6, l = t & 63;
  __shared__ float SLN[SS * DD];
  __shared__ unsigned short A1[16 * DD];
  float muv = mu[t];
  float sgv = __expf(lsg[t]);
  #pragma unroll
  for(int s = 0; s < SS; ++s){
    float v = muv + sgv * noise[(size_t)b * 2048 + s * 256 + t];
    slots[(size_t)b * 2048 + s * 256 + t] = v;
    SLN[s * 256 + t] = v;
  }
  __syncthreads();
  float4 g4 = ((const float4*)lng)[l], bb4 = ((const float4*)lnb)[l];
  for(int sh = 0; sh < 2; ++sh){
    int s = w * 2 + sh;
    float4 x4 = ((const float4*)(SLN + s * 256))[l];
    float s1 = x4.x + x4.y + x4.z + x4.w;
    float s2 = x4.x*x4.x + x4.y*x4.y + x4.z*x4.z + x4.w*x4.w;
    #pragma unroll
    for(int o = 32; o >= 1; o >>= 1){ s1 += __shfl_xor(s1, o); s2 += __shfl_xor(s2, o); }
    float mean = s1 * (1.0f/256.0f);
    float inv  = rsqrtf(s2 * (1.0f/256.0f) - mean*mean + 1e-5f);
    float y0 = (x4.x-mean)*inv*g4.x + bb4.x;
    float y1 = (x4.y-mean)*inv*g4.y + bb4.y;
    float y2 = (x4.z-mean)*inv*g4.z + bb4.z;
    float y3 = (x4.w-mean)*inv*g4.w + bb4.w;
    int byte = s * 512 + ((l * 8) ^ ((s & 7) << 4));
    *(uint2*)((char*)A1 + byte) = make_uint2(pk2(y0,y1), pk2(y2,y3));
  }
  __syncthreads();
  const int m = l & 15;
  short8 af[8];
  #pragma unroll
  for(int kk = 0; kk < 8; ++kk){
    int ab = m * 512 + (((kk * 64) + ((l >> 4) << 4)) ^ ((m & 7) << 4));
    af[kk] = *(const short8*)((const char*)A1 + ab);
  }
  #pragma unroll
  for(int i = 0; i < 4; ++i){
    int et = w + i * 4;
    f32x4 c = (f32x4){0,0,0,0};
    #pragma unroll
    for(int kk = 0; kk < 8; ++kk) c = MFMA(af[kk], wqkp[((kk * 16 + et) << 6) + l], c);
    int e = et * 16 + (l & 15);
    #pragma unroll
    for(int j = 0; j < 4; ++j){
      int s = ((l >> 4) << 2) + j;
      if(s < 8) qbuf[(size_t)b * 2048 + s * 256 + e] = c[j];
    }
  }
}

// MFMA flash partials: logits = qk@x^T (B=x row-major), softmax,
// PX = P@x with the x chunk re-staged transposed through LDS (L2-hot re-read).
__global__ __launch_bounds__(256, 3) void attn_kernel(
    const unsigned short* __restrict__ x_, const float* __restrict__ qbuf,
    float* __restrict__ pupd, float* __restrict__ pms)
{
  const int blk = blockIdx.x;
  const int b = blk >> 3, c = blk & 7;
  const int t = threadIdx.x, w = t >> 6, l = t & 63;
  __shared__ float ls[8 * LSP];            // 16.5 KB exp(logits)
  __shared__ __align__(16) char xv[256 * 128];  // 32 KB transposed sub-chunk [256d][64n]

  const int m = l & 15, lg = l >> 4;
  short8 aq[8];
  #pragma unroll
  for(int kk = 0; kk < 8; ++kk){
    if(m < 8){
      const float* qp = qbuf + (size_t)b * 2048 + m * 256 + kk * 32 + (lg << 3);
      float4 qa = *(const float4*)qp;
      float4 qb = *(const float4*)(qp + 4);
      int4 pv = make_int4((int)pk2(qa.x,qa.y), (int)pk2(qa.z,qa.w),
                          (int)pk2(qb.x,qb.y), (int)pk2(qb.z,qb.w));
      aq[kk] = __builtin_bit_cast(short8, pv);
    } else {
      aq[kk] = (short8){0,0,0,0,0,0,0,0};
    }
  }

  const unsigned short* xb = x_ + ((size_t)b * NN + (size_t)c * CHK) * DD;
  #pragma unroll
  for(int nt = 0; nt < 8; ++nt){
    int nb = w * 128 + nt * 16;
    f32x4 acc = (f32x4){0,0,0,0};
    #pragma unroll
    for(int kk = 0; kk < 8; ++kk){
      short8 bk = *(const short8*)(xb + (size_t)(nb + m) * DD + kk * 32 + (lg << 3));
      acc = MFMA(aq[kk], bk, acc);
    }
    if(l < 32){
      int s4 = (l >> 4) * 4;
      #pragma unroll
      for(int j = 0; j < 4; ++j) ls[(s4 + j) * LSP + nb + m] = acc[j];
    }
  }
  __syncthreads();

  for(int sh = 0; sh < 2; ++sh){
    int s = w * 2 + sh;
    float* base = ls + s * LSP;
    float4 v0 = *(float4*)(base + l * 4);
    float4 v1 = *(float4*)(base + 256 + l * 4);
    float mx = fmaxf(fmaxf(fmaxf(v0.x,v0.y),fmaxf(v0.z,v0.w)),
                     fmaxf(fmaxf(v1.x,v1.y),fmaxf(v1.z,v1.w)));
    #pragma unroll
    for(int o = 32; o >= 1; o >>= 1) mx = fmaxf(mx, __shfl_xor(mx, o));
    float e0 = __expf(v0.x-mx), e1 = __expf(v0.y-mx), e2 = __expf(v0.z-mx), e3 = __expf(v0.w-mx);
    float e4 = __expf(v1.x-mx), e5 = __expf(v1.y-mx), e6 = __expf(v1.z-mx), e7 = __expf(v1.w-mx);
    float sm = e0+e1+e2+e3+e4+e5+e6+e7;
    #pragma unroll
    for(int o = 32; o >= 1; o >>= 1) sm += __shfl_xor(sm, o);
    *(float4*)(base + l * 4)       = make_float4(e0,e1,e2,e3);
    *(float4*)(base + 256 + l * 4) = make_float4(e4,e5,e6,e7);
    if(l == 0){
      pms[(((size_t)b * 8 + c) * 8 + s) * 2    ] = mx;
      pms[(((size_t)b * 8 + c) * 8 + s) * 2 + 1] = sm;
    }
  }
  __syncthreads();

  short8 pa[16];
  #pragma unroll
  for(int kk = 0; kk < 16; ++kk){
    if(m < 8){
      const float* pp = ls + m * LSP + kk * 32 + (lg << 3);
      int4 pv = make_int4((int)pk2(pp[0],pp[1]), (int)pk2(pp[2],pp[3]),
                          (int)pk2(pp[4],pp[5]), (int)pk2(pp[6],pp[7]));
      pa[kk] = __builtin_bit_cast(short8, pv);
    } else {
      pa[kk] = (short8){0,0,0,0,0,0,0,0};
    }
  }

  // PV: loop 64-n sub-chunks; stage transposed [d][n] into LDS from the L2-hot chunk.
  f32x4 acc[4];
  #pragma unroll
  for(int dt = 0; dt < 4; ++dt) acc[dt] = (f32x4){0,0,0,0};
  const int p = t & 31, db = t >> 5;   // n-pair 0..31, d-block 0..7 (32 d each)
  for(int ng = 0; ng < 8; ++ng){
    if(ng) __syncthreads();
    {
      const unsigned short* rA = xb + (size_t)(ng * 64 + 2 * p) * DD + db * 32;
      const unsigned short* rB = rA + DD;
      #pragma unroll
      for(int q = 0; q < 4; ++q){
        uint4 va = *(const uint4*)(rA + q * 8);
        uint4 vb = *(const uint4*)(rB + q * 8);
        unsigned int wa[4] = {va.x, va.y, va.z, va.w};
        unsigned int wb[4] = {vb.x, vb.y, vb.z, vb.w};
        #pragma unroll
        for(int h = 0; h < 4; ++h){
          int d0 = db * 32 + q * 8 + h * 2;
          unsigned int a = wa[h], bv = wb[h];
          unsigned int v0 = (a & 0xFFFFu) | (bv << 16);
          unsigned int v1 = (a >> 16) | (bv & 0xFFFF0000u);
          *(unsigned int*)(xv + d0 * 128 + ((p * 4) ^ ((d0 & 7) << 4))) = v0;
          int d1 = d0 + 1;
          *(unsigned int*)(xv + d1 * 128 + ((p * 4) ^ ((d1 & 7) << 4))) = v1;
        }
      }
    }
    __syncthreads();
    #pragma unroll
    for(int kkloc = 0; kkloc < 2; ++kkloc){
      int kk = ng * 2 + kkloc;
      #pragma unroll
      for(int dt = 0; dt < 4; ++dt){
        int d = w * 64 + dt * 16 + m;
        short8 bv = *(const short8*)(xv + d * 128 + ((kkloc * 64 + lg * 16) ^ ((d & 7) << 4)));
        acc[dt] = MFMA(pa[kk], bv, acc[dt]);
      }
    }
  }
  if(l < 32){
    int s4 = (l >> 4) * 4;
    #pragma unroll
    for(int dt = 0; dt < 4; ++dt){
      int d0 = w * 64 + dt * 16;
      #pragma unroll
      for(int j = 0; j < 4; ++j)
        pupd[((size_t)b * 8 + c) * 2048 + (s4 + j) * 256 + d0 + m] = acc[dt][j];
    }
  }
}

// Combine PX partials -> PX/Z ; GRU (gx = PXn@M^T) ; residual MLP ; slots ; LN ; next qk
__global__ __launch_bounds__(1024, 1) void update_kernel(
    const float* __restrict__ pupd, const float* __restrict__ pms,
    float* __restrict__ slots, float* __restrict__ qbuf,
    const short8* __restrict__ mp, const short8* __restrict__ whh,
    const float* __restrict__ bih, const float* __restrict__ bhh,
    const short8* __restrict__ w1p, const float* __restrict__ b1v,
    const short8* __restrict__ w2p, const float* __restrict__ b2v,
    const float* __restrict__ lnsg, const float* __restrict__ lnsb,
    const float* __restrict__ lnmg, const float* __restrict__ lnmb,
    const short8* __restrict__ wqkp,
    float* __restrict__ dout, const int last)
{
  const int b = blockIdx.x, t = threadIdx.x, w = t >> 6, l = t & 63;
  __shared__ unsigned short A1[16 * 256];
  __shared__ unsigned short A2[16 * 256];
  __shared__ unsigned short A3[16 * 512];
  __shared__ float GR[8 * 256], GZ[8 * 256], GXN[8 * 256], GHN[8 * 256];
  __shared__ float SL[8 * 256];
  __shared__ float PMS[128];

  if(t < 128) PMS[t] = pms[(size_t)b * 128 + t];
  __syncthreads();

  const int col = t & 255, sg = t >> 8;
  float upd[2], pv[2];
  #pragma unroll
  for(int ss = 0; ss < 2; ++ss){
    int s = sg * 2 + ss;
    float mx = -1e30f;
    #pragma unroll
    for(int cc = 0; cc < 8; ++cc) mx = fmaxf(mx, PMS[(cc * 8 + s) * 2]);
    float Z = 0.f, u = 0.f;
    #pragma unroll
    for(int cc = 0; cc < 8; ++cc){
      float e = __expf(PMS[(cc * 8 + s) * 2] - mx);
      Z += e * PMS[(cc * 8 + s) * 2 + 1];
      u += e * pupd[((size_t)b * 8 + cc) * 2048 + s * 256 + col];
    }
    upd[ss] = u / Z;
    pv[ss]  = slots[(size_t)b * 2048 + s * 256 + col];
  }
  #pragma unroll
  for(int ss = 0; ss < 2; ++ss){
    int s = sg * 2 + ss;
    int byte = s * 512 + ((col * 2) ^ ((s & 7) << 4));
    *(unsigned short*)((char*)A1 + byte) = f2bf(upd[ss]);
    *(unsigned short*)((char*)A2 + byte) = f2bf(pv[ss]);
  }
  __syncthreads();

  {
    const int m = l & 15;
    short8 a1f[8], a2f[8];
    #pragma unroll
    for(int kk = 0; kk < 8; ++kk){
      int ab = m * 512 + (((kk * 64) + ((l >> 4) << 4)) ^ ((m & 7) << 4));
      a1f[kk] = *(const short8*)((const char*)A1 + ab);
      a2f[kk] = *(const short8*)((const char*)A2 + ab);
    }
    #pragma unroll
    for(int i = 0; i < 3; ++i){
      int et = w + i * 16;
      f32x4 c1 = (f32x4){0,0,0,0}, c2 = (f32x4){0,0,0,0};
      #pragma unroll
      for(int kk = 0; kk < 8; ++kk){
        c1 = MFMA(a1f[kk], mp[((kk * 48 + et) << 6) + l], c1);
        c2 = MFMA(a2f[kk], whh[((kk * 48 + et) << 6) + l], c2);
      }
      int e = et * 16 + (l & 15);
      float xb = bih[e], hb = bhh[e];
      #pragma unroll
      for(int j = 0; j < 4; ++j){
        int s = ((l >> 4) << 2) + j;
        if(s < 8){
          float xx = c1[j] + xb, h = c2[j] + hb;
          if(i == 0)      GR[s * 256 + e      ] = 1.f/(1.f + __expf(-(xx + h)));
          else if(i == 1) GZ[s * 256 + (e-256)] = 1.f/(1.f + __expf(-(xx + h)));
          else { GXN[s * 256 + (e-512)] = xx; GHN[s * 256 + (e-512)] = h; }
        }
      }
    }
  }
  __syncthreads();

  #pragma unroll
  for(int ss = 0; ss < 2; ++ss){
    int s = sg * 2 + ss, idx = s * 256 + col;
    float r = GR[idx], z = GZ[idx], xn = GXN[idx], hn = GHN[idx];
    float nn = tanhf(xn + r * hn);
    SL[idx] = (1.f - z) * nn + z * pv[ss];
  }
  __syncthreads();

  if(w < 8){
    float4 g4 = ((const float4*)lnmg)[l], bb4 = ((const float4*)lnmb)[l];
    int s = w;
    float4 x4 = ((const float4*)(SL + s * 256))[l];
    float s1 = x4.x + x4.y + x4.z + x4.w;
    float s2 = x4.x*x4.x + x4.y*x4.y + x4.z*x4.z + x4.w*x4.w;
    #pragma unroll
    for(int o = 32; o >= 1; o >>= 1){ s1 += __shfl_xor(s1, o); s2 += __shfl_xor(s2, o); }
    float mean = s1 * (1.0f/256.0f);
    float inv  = rsqrtf(s2 * (1.0f/256.0f) - mean*mean + 1e-5f);
    float y0 = (x4.x-mean)*inv*g4.x + bb4.x;
    float y1 = (x4.y-mean)*inv*g4.y + bb4.y;
    float y2 = (x4.z-mean)*inv*g4.z + bb4.z;
    float y3 = (x4.w-mean)*inv*g4.w + bb4.w;
    int byte = s * 512 + ((l * 8) ^ ((s & 7) << 4));
    *(uint2*)((char*)A1 + byte) = make_uint2(pk2(y0,y1), pk2(y2,y3));
  }
  __syncthreads();

  {
    const int m = l & 15;
    short8 af[8];
    #pragma unroll
    for(int kk = 0; kk < 8; ++kk){
      int ab = m * 512 + (((kk * 64) + ((l >> 4) << 4)) ^ ((m & 7) << 4));
      af[kk] = *(const short8*)((const char*)A1 + ab);
    }
    #pragma unroll
    for(int i = 0; i < 2; ++i){
      int et = w + i * 16;
      f32x4 c = (f32x4){0,0,0,0};
      #pragma unroll
      for(int kk = 0; kk < 8; ++kk) c = MFMA(af[kk], w1p[((kk * 32 + et) << 6) + l], c);
      int e = et * 16 + (l & 15);
      float bb = b1v[e];
      #pragma unroll
      for(int j = 0; j < 4; ++j){
        int s = ((l >> 4) << 2) + j;
        if(s < 8){
          float h = fmaxf(c[j] + bb, 0.f);
          int byte = s * 1024 + ((e * 2) ^ ((s & 7) << 4));
          *(unsigned short*)((char*)A3 + byte) = f2bf(h);
        }
      }
    }
  }
  __syncthreads();

  {
    const int m = l & 15;
    short8 af[16];
    #pragma unroll
    for(int kk = 0; kk < 16; ++kk){
      int ab = m * 1024 + (((kk * 64) + ((l >> 4) << 4)) ^ ((m & 7) << 4));
      af[kk] = *(const short8*)((const char*)A3 + ab);
    }
    {
      int et = w;
      f32x4 c = (f32x4){0,0,0,0};
      #pragma unroll
      for(int kk = 0; kk < 16; ++kk) c = MFMA(af[kk], w2p[((kk * 16 + et) << 6) + l], c);
      int e = et * 16 + (l & 15);
      float bb = b2v[e];
      #pragma unroll
      for(int j = 0; j < 4; ++j){
        int s = ((l >> 4) << 2) + j;
        if(s < 8) GR[s * 256 + e] = SL[s * 256 + e] + c[j] + bb;
      }
    }
  }
  __syncthreads();

  for(int i = t; i < 2048; i += 1024){
    float v = GR[i];
    slots[(size_t)b * 2048 + i] = v;
    if(last) dout[(size_t)b * 2048 + i] = v;
  }
  if(w < 8){
    float4 g4 = ((const float4*)lnsg)[l], bb4 = ((const float4*)lnsb)[l];
    int s = w;
    float4 x4 = ((const float4*)(GR + s * 256))[l];
    float s1 = x4.x + x4.y + x4.z + x4.w;
    float s2 = x4.x*x4.x + x4.y*x4.y + x4.z*x4.z + x4.w*x4.w;
    #pragma unroll
    for(int o = 32; o >= 1; o >>= 1){ s1 += __shfl_xor(s1, o); s2 += __shfl_xor(s2, o); }
    float mean = s1 * (1.0f/256.0f);
    float inv  = rsqrtf(s2 * (1.0f/256.0f) - mean*mean + 1e-5f);
    float y0 = (x4.x-mean)*inv*g4.x + bb4.x;
    float y1 = (x4.y-mean)*inv*g4.y + bb4.y;
    float y2 = (x4.z-mean)*inv*g4.z + bb4.z;
    float y3 = (x4.w-mean)*inv*g4.w + bb4.w;
    int byte = s * 512 + ((l * 8) ^ ((s & 7) << 4));
    *(uint2*)((char*)A1 + byte) = make_uint2(pk2(y0,y1), pk2(y2,y3));
  }
  __syncthreads();
  {
    const int m = l & 15;
    short8 af[8];
    #pragma unroll
    for(int kk = 0; kk < 8; ++kk){
      int ab = m * 512 + (((kk * 64) + ((l >> 4) << 4)) ^ ((m & 7) << 4));
      af[kk] = *(const short8*)((const char*)A1 + ab);
    }
    {
      int et = w;
      f32x4 c = (f32x4){0,0,0,0};
      #pragma unroll
      for(int kk = 0; kk < 8; ++kk) c = MFMA(af[kk], wqkp[((kk * 16 + et) << 6) + l], c);
      int e = et * 16 + (l & 15);
      #pragma unroll
      for(int j = 0; j < 4; ++j){
        int s = ((l >> 4) << 2) + j;
        if(s < 8) qbuf[(size_t)b * 2048 + s * 256 + e] = c[j];
      }
    }
  }
}

extern "C" void kernel_launch(void* const* d_in, const int* in_sizes, int n_in,
                              void* d_out, int out_size, void* d_ws, size_t ws_size,
                              hipStream_t stream)
{
  const float* inp   = (const float*)d_in[0];
  const float* noise = (const float*)d_in[1];
  const float* mu    = (const float*)d_in[2];
  const float* lsg   = (const float*)d_in[3];
  const float* lngi  = (const float*)d_in[4];
  const float* lnbi  = (const float*)d_in[5];
  const float* lngs  = (const float*)d_in[6];
  const float* lnbs  = (const float*)d_in[7];
  const float* lngm  = (const float*)d_in[8];
  const float* lnbm  = (const float*)d_in[9];
  const float* Wq    = (const float*)d_in[10];
  const float* Wk    = (const float*)d_in[11];
  const float* Wv    = (const float*)d_in[12];
  const float* Wih   = (const float*)d_in[13];
  const float* Whh   = (const float*)d_in[14];
  const float* bih   = (const float*)d_in[15];
  const float* bhh   = (const float*)d_in[16];
  const float* W1    = (const float*)d_in[17];
  const float* b1    = (const float*)d_in[18];
  const float* W2    = (const float*)d_in[19];
  const float* b2    = (const float*)d_in[20];
  float* dout = (float*)d_out;

  char* ws = (char*)d_ws;
  size_t off = 0;
  unsigned short* x   = (unsigned short*)(ws + off); off += (size_t)BB*NN*DD*2;
  short8* wqkp= (short8*)(ws + off); off += (size_t)256*256*2;
  short8* mp  = (short8*)(ws + off); off += (size_t)768*256*2;
  short8* whhp= (short8*)(ws + off); off += (size_t)768*256*2;
  short8* w1p = (short8*)(ws + off); off += (size_t)512*256*2;
  short8* w2p = (short8*)(ws + off); off += (size_t)256*512*2;
  float* wqkT = (float*)(ws + off);  off += (size_t)256*256*4;
  float* mf32 = (float*)(ws + off);  off += (size_t)768*256*4;
  float* qbuf = (float*)(ws + off);  off += (size_t)512*256*4;
  float* slots= (float*)(ws + off);  off += (size_t)512*256*4;
  float* pupd = (float*)(ws + off);  off += (size_t)64*8*8*256*4;
  float* pms  = (float*)(ws + off);  off += (size_t)64*8*8*2*4;

  wqkT_kernel<<<256, 256, 0, stream>>>(Wq, Wk, wqkT);
  m_kernel<<<768, 256, 0, stream>>>(Wih, Wv, mf32);

  PackDesc pd;
  const float* srcs[5] = {wqkT, mf32, Whh, W1, W2};
  unsigned short* dsts[5] = {(unsigned short*)wqkp, (unsigned short*)mp,
                             (unsigned short*)whhp, (unsigned short*)w1p,
                             (unsigned short*)w2p};
  int ets[5] = {16, 48, 48, 32, 16};
  int ks [5] = {256, 256, 256, 256, 512};
  int cum = 0;
  for(int i = 0; i < 5; ++i){
    pd.src[i] = srcs[i]; pd.dst[i] = dsts[i]; pd.ET[i] = ets[i]; pd.K[i] = ks[i];
    pd.blkStart[i] = cum;
    cum += (ets[i] * 16 * ks[i] + 255) / 256;
  }
  pd.blkStart[5] = cum;
  pack_all_kernel<<<cum, 256, 0, stream>>>(pd);

  ln_kernel<<<4096, 256, 0, stream>>>(inp, lngi, lnbi, x);
  init_kernel<<<64, 256, 0, stream>>>(noise, mu, lsg, lngs, lnbs, wqkp, slots, qbuf);

  for(int it = 0; it < 3; ++it){
    attn_kernel<<<512, 256, 0, stream>>>(x, qbuf, pupd, pms);
    update_kernel<<<64, 1024, 0, stream>>>(pupd, pms, slots, qbuf, mp, whhp,
        bih, bhh, w1p, b1, w2p, b2, lngs, lnbs, lngm, lnbm, wqkp, dout, (it == 2) ? 1 : 0);
  }
}

// Round 13
// 346.143 us; speedup vs baseline: 1.4025x; 1.0581x over previous
//
#include <hip/hip_runtime.h>

// Slot attention, MI355X. B=64,N=4096,S=8,D=256,H=512,ITERS=3.
// K,V never materialized (Wqk = scale*Wq^T@Wk, M = W_ih@Wv folded).
// Single-copy x: PV re-reads the QK chunk via an LDS transpose (no xT buffer),
// with prefetched (issue-early) global loads hiding latency under PV MFMAs.
#define BB 64
#define NN 4096
#define SS 8
#define DD 256
#define HH 512
#define NCH 8
#define CHK 512
#define LSP 516   // padded row stride (f32) for logits LDS

typedef __attribute__((ext_vector_type(4))) float f32x4;
typedef __attribute__((ext_vector_type(8))) short short8;
typedef __attribute__((ext_vector_type(8))) __bf16 bf16x8;

static __device__ __forceinline__ f32x4 MFMA(short8 a, short8 b, f32x4 c){
  return __builtin_amdgcn_mfma_f32_16x16x32_bf16(
      __builtin_bit_cast(bf16x8, a), __builtin_bit_cast(bf16x8, b), c, 0, 0, 0);
}

static __device__ __forceinline__ unsigned short f2bf(float f){
  unsigned int x = __builtin_bit_cast(unsigned int, f);
  x += 0x7FFFu + ((x >> 16) & 1u);
  return (unsigned short)(x >> 16);
}

static __device__ __forceinline__ unsigned int pk2(float a, float b){
  return (unsigned int)f2bf(a) | ((unsigned int)f2bf(b) << 16);
}

// ---- merged precompute:
//   blk <  256: wqkT[d2][d1] = scale * sum_e Wq[e][d1]*Wk[e][d2]
//   blk >= 256: m[e][c]     = sum_d Wih[e][d]*Wv[d][c]
__global__ __launch_bounds__(256, 4) void pre_kernel(
    const float* __restrict__ Wq, const float* __restrict__ Wk,
    const float* __restrict__ Wih, const float* __restrict__ Wv,
    float* __restrict__ wqkT, float* __restrict__ mf32)
{
  __shared__ float sh[256];
  const int blk = blockIdx.x, t = threadIdx.x;
  if(blk < 256){
    const int d2 = blk;
    sh[t] = Wk[(size_t)t * 256 + d2];
    __syncthreads();
    float acc = 0.f;
    #pragma unroll 8
    for(int e = 0; e < 256; ++e) acc += sh[e] * Wq[(size_t)e * 256 + t];
    wqkT[(size_t)d2 * 256 + t] = acc * 0.0625f;
  } else {
    const int e = blk - 256;
    sh[t] = Wih[(size_t)e * 256 + t];
    __syncthreads();
    float acc = 0.f;
    #pragma unroll 8
    for(int d = 0; d < 256; ++d) acc += sh[d] * Wv[(size_t)d * 256 + t];
    mf32[(size_t)e * 256 + t] = acc;
  }
}

// ---- merged weight pack: W(E=ET*16, K) fp32 row-major -> bf16 MFMA fragments
struct PackDesc {
  const float* src[5];
  unsigned short* dst[5];
  int ET[5];
  int K[5];
  int blkStart[6];
};

__global__ void pack_all_kernel(PackDesc pd){
  int blk = blockIdx.x;
  int seg = 0;
  #pragma unroll
  for(int i = 1; i < 5; ++i) if(blk >= pd.blkStart[i]) seg = i;
  int tid = (blk - pd.blkStart[seg]) * 256 + threadIdx.x;
  int ET = pd.ET[seg], K = pd.K[seg];
  if(tid >= ET * 16 * K) return;
  int i    = tid & 7;
  int lane = (tid >> 3) & 63;
  int rest = tid >> 9;
  int et = rest % ET;
  int kk = rest / ET;
  int row = et * 16 + (lane & 15);
  int col = kk * 32 + ((lane >> 4) << 3) + i;
  pd.dst[seg][tid] = f2bf(pd.src[seg][(size_t)row * K + col]);
}

// LN(inputs) -> x (bf16 row-major). Pure streaming, no LDS.
__global__ __launch_bounds__(256, 4) void ln_kernel(
    const float* __restrict__ inp, const float* __restrict__ g, const float* __restrict__ bta,
    unsigned short* __restrict__ x)
{
  const int t = threadIdx.x, w = t >> 6, l = t & 63;
  const size_t row0 = (size_t)blockIdx.x * 64;
  const int li = l & 15, lg = l >> 4;

  float4 gg[4], bb[4];
  #pragma unroll
  for(int q = 0; q < 4; ++q){
    gg[q] = ((const float4*)g)[li + q * 16];
    bb[q] = ((const float4*)bta)[li + q * 16];
  }
  #pragma unroll
  for(int rr = 0; rr < 4; ++rr){
    int r = w * 16 + rr * 4 + lg;
    const float4* rp = (const float4*)(inp + (row0 + r) * DD);
    float4 xv[4];
    #pragma unroll
    for(int q = 0; q < 4; ++q) xv[q] = rp[li + q * 16];
    float s1 = 0.f, s2 = 0.f;
    #pragma unroll
    for(int q = 0; q < 4; ++q){
      s1 += xv[q].x + xv[q].y + xv[q].z + xv[q].w;
      s2 += xv[q].x*xv[q].x + xv[q].y*xv[q].y + xv[q].z*xv[q].z + xv[q].w*xv[q].w;
    }
    #pragma unroll
    for(int o = 8; o >= 1; o >>= 1){ s1 += __shfl_xor(s1, o); s2 += __shfl_xor(s2, o); }
    float mean = s1 * (1.0f/256.0f);
    float inv  = rsqrtf(s2 * (1.0f/256.0f) - mean*mean + 1e-5f);
    #pragma unroll
    for(int q = 0; q < 4; ++q){
      float y0 = (xv[q].x-mean)*inv*gg[q].x + bb[q].x;
      float y1 = (xv[q].y-mean)*inv*gg[q].y + bb[q].y;
      float y2 = (xv[q].z-mean)*inv*gg[q].z + bb[q].z;
      float y3 = (xv[q].w-mean)*inv*gg[q].w + bb[q].w;
      *(uint2*)((char*)x + (row0 + r) * 512 + q * 128 + li * 8) =
          make_uint2(pk2(y0,y1), pk2(y2,y3));
    }
  }
}

// slots0 = mu + exp(log_sigma)*noise ; qk = LN_slots(slots0) @ Wqk
__global__ __launch_bounds__(256, 1) void init_kernel(
    const float* __restrict__ noise, const float* __restrict__ mu, const float* __restrict__ lsg,
    const float* __restrict__ lng, const float* __restrict__ lnb,
    const short8* __restrict__ wqkp, float* __restrict__ slots, float* __restrict__ qbuf)
{
  const int b = blockIdx.x, t = threadIdx.x, w = t >> 6, l = t & 63;
  __shared__ float SLN[SS * DD];
  __shared__ unsigned short A1[16 * DD];
  float muv = mu[t];
  float sgv = __expf(lsg[t]);
  #pragma unroll
  for(int s = 0; s < SS; ++s){
    float v = muv + sgv * noise[(size_t)b * 2048 + s * 256 + t];
    slots[(size_t)b * 2048 + s * 256 + t] = v;
    SLN[s * 256 + t] = v;
  }
  __syncthreads();
  float4 g4 = ((const float4*)lng)[l], bb4 = ((const float4*)lnb)[l];
  for(int sh = 0; sh < 2; ++sh){
    int s = w * 2 + sh;
    float4 x4 = ((const float4*)(SLN + s * 256))[l];
    float s1 = x4.x + x4.y + x4.z + x4.w;
    float s2 = x4.x*x4.x + x4.y*x4.y + x4.z*x4.z + x4.w*x4.w;
    #pragma unroll
    for(int o = 32; o >= 1; o >>= 1){ s1 += __shfl_xor(s1, o); s2 += __shfl_xor(s2, o); }
    float mean = s1 * (1.0f/256.0f);
    float inv  = rsqrtf(s2 * (1.0f/256.0f) - mean*mean + 1e-5f);
    float y0 = (x4.x-mean)*inv*g4.x + bb4.x;
    float y1 = (x4.y-mean)*inv*g4.y + bb4.y;
    float y2 = (x4.z-mean)*inv*g4.z + bb4.z;
    float y3 = (x4.w-mean)*inv*g4.w + bb4.w;
    int byte = s * 512 + ((l * 8) ^ ((s & 7) << 4));
    *(uint2*)((char*)A1 + byte) = make_uint2(pk2(y0,y1), pk2(y2,y3));
  }
  __syncthreads();
  const int m = l & 15;
  short8 af[8];
  #pragma unroll
  for(int kk = 0; kk < 8; ++kk){
    int ab = m * 512 + (((kk * 64) + ((l >> 4) << 4)) ^ ((m & 7) << 4));
    af[kk] = *(const short8*)((const char*)A1 + ab);
  }
  #pragma unroll
  for(int i = 0; i < 4; ++i){
    int et = w + i * 4;
    f32x4 c = (f32x4){0,0,0,0};
    #pragma unroll
    for(int kk = 0; kk < 8; ++kk) c = MFMA(af[kk], wqkp[((kk * 16 + et) << 6) + l], c);
    int e = et * 16 + (l & 15);
    #pragma unroll
    for(int j = 0; j < 4; ++j){
      int s = ((l >> 4) << 2) + j;
      if(s < 8) qbuf[(size_t)b * 2048 + s * 256 + e] = c[j];
    }
  }
}

// MFMA flash partials: logits = qk@x^T (B=x row-major), softmax,
// PX = P@x with the x chunk re-staged transposed through LDS (L2/L3-hot re-read).
// PV staging loads for subtile ng+1 are issued BEFORE ng's MFMA phase (T14).
__global__ __launch_bounds__(256, 3) void attn_kernel(
    const unsigned short* __restrict__ x_, const float* __restrict__ qbuf,
    float* __restrict__ pupd, float* __restrict__ pms)
{
  const int blk = blockIdx.x;
  const int b = blk >> 3, c = blk & 7;
  const int t = threadIdx.x, w = t >> 6, l = t & 63;
  __shared__ float ls[8 * LSP];            // 16.5 KB exp(logits)
  __shared__ __align__(16) char xv[256 * 128];  // 32 KB transposed sub-chunk [256d][64n]

  const int m = l & 15, lg = l >> 4;
  short8 aq[8];
  #pragma unroll
  for(int kk = 0; kk < 8; ++kk){
    if(m < 8){
      const float* qp = qbuf + (size_t)b * 2048 + m * 256 + kk * 32 + (lg << 3);
      float4 qa = *(const float4*)qp;
      float4 qb = *(const float4*)(qp + 4);
      int4 pv = make_int4((int)pk2(qa.x,qa.y), (int)pk2(qa.z,qa.w),
                          (int)pk2(qb.x,qb.y), (int)pk2(qb.z,qb.w));
      aq[kk] = __builtin_bit_cast(short8, pv);
    } else {
      aq[kk] = (short8){0,0,0,0,0,0,0,0};
    }
  }

  const unsigned short* xb = x_ + ((size_t)b * NN + (size_t)c * CHK) * DD;
  #pragma unroll
  for(int nt = 0; nt < 8; ++nt){
    int nb = w * 128 + nt * 16;
    f32x4 acc = (f32x4){0,0,0,0};
    #pragma unroll
    for(int kk = 0; kk < 8; ++kk){
      short8 bk = *(const short8*)(xb + (size_t)(nb + m) * DD + kk * 32 + ((l >> 4) << 3));
      acc = MFMA(aq[kk], bk, acc);
    }
    if(l < 32){
      int s4 = (l >> 4) * 4;
      #pragma unroll
      for(int j = 0; j < 4; ++j) ls[(s4 + j) * LSP + nb + m] = acc[j];
    }
  }
  __syncthreads();

  for(int sh = 0; sh < 2; ++sh){
    int s = w * 2 + sh;
    float* base = ls + s * LSP;
    float4 v0 = *(float4*)(base + l * 4);
    float4 v1 = *(float4*)(base + 256 + l * 4);
    float mx = fmaxf(fmaxf(fmaxf(v0.x,v0.y),fmaxf(v0.z,v0.w)),
                     fmaxf(fmaxf(v1.x,v1.y),fmaxf(v1.z,v1.w)));
    #pragma unroll
    for(int o = 32; o >= 1; o >>= 1) mx = fmaxf(mx, __shfl_xor(mx, o));
    float e0 = __expf(v0.x-mx), e1 = __expf(v0.y-mx), e2 = __expf(v0.z-mx), e3 = __expf(v0.w-mx);
    float e4 = __expf(v1.x-mx), e5 = __expf(v1.y-mx), e6 = __expf(v1.z-mx), e7 = __expf(v1.w-mx);
    float sm = e0+e1+e2+e3+e4+e5+e6+e7;
    #pragma unroll
    for(int o = 32; o >= 1; o >>= 1) sm += __shfl_xor(sm, o);
    *(float4*)(base + l * 4)       = make_float4(e0,e1,e2,e3);
    *(float4*)(base + 256 + l * 4) = make_float4(e4,e5,e6,e7);
    if(l == 0){
      pms[(((size_t)b * 8 + c) * 8 + s) * 2    ] = mx;
      pms[(((size_t)b * 8 + c) * 8 + s) * 2 + 1] = sm;
    }
  }
  __syncthreads();

  short8 pa[16];
  #pragma unroll
  for(int kk = 0; kk < 16; ++kk){
    if(m < 8){
      const float* pp = ls + m * LSP + kk * 32 + ((l >> 4) << 3);
      int4 pv = make_int4((int)pk2(pp[0],pp[1]), (int)pk2(pp[2],pp[3]),
                          (int)pk2(pp[4],pp[5]), (int)pk2(pp[6],pp[7]));
      pa[kk] = __builtin_bit_cast(short8, pv);
    } else {
      pa[kk] = (short8){0,0,0,0,0,0,0,0};
    }
  }

  // PV: loop 64-n sub-chunks; stage transposed [d][n] into LDS.
  // Global loads for subtile ng+1 are issued before ng's MFMA phase.
  f32x4 acc[4];
  #pragma unroll
  for(int dt = 0; dt < 4; ++dt) acc[dt] = (f32x4){0,0,0,0};
  const int p = t & 31, db = t >> 5;   // n-pair 0..31, d-block 0..7 (32 d each)

  uint4 va0, va1, va2, va3, vb0, vb1, vb2, vb3;
  {
    const unsigned short* rA = xb + (size_t)(2 * p) * DD + db * 32;
    const unsigned short* rB = rA + DD;
    va0 = *(const uint4*)(rA);      vb0 = *(const uint4*)(rB);
    va1 = *(const uint4*)(rA + 8);  vb1 = *(const uint4*)(rB + 8);
    va2 = *(const uint4*)(rA + 16); vb2 = *(const uint4*)(rB + 16);
    va3 = *(const uint4*)(rA + 24); vb3 = *(const uint4*)(rB + 24);
  }

  for(int ng = 0; ng < 8; ++ng){
    if(ng) __syncthreads();
    {
      uint4 VA[4] = {va0, va1, va2, va3};
      uint4 VB[4] = {vb0, vb1, vb2, vb3};
      #pragma unroll
      for(int q = 0; q < 4; ++q){
        unsigned int wa[4] = {VA[q].x, VA[q].y, VA[q].z, VA[q].w};
        unsigned int wb[4] = {VB[q].x, VB[q].y, VB[q].z, VB[q].w};
        #pragma unroll
        for(int h = 0; h < 4; ++h){
          int d0 = db * 32 + q * 8 + h * 2;
          unsigned int a = wa[h], bv = wb[h];
          unsigned int v0 = (a & 0xFFFFu) | (bv << 16);
          unsigned int v1 = (a >> 16) | (bv & 0xFFFF0000u);
          *(unsigned int*)(xv + d0 * 128 + ((p * 4) ^ ((d0 & 7) << 4))) = v0;
          int d1 = d0 + 1;
          *(unsigned int*)(xv + d1 * 128 + ((p * 4) ^ ((d1 & 7) << 4))) = v1;
        }
      }
    }
    __syncthreads();
    if(ng < 7){
      const unsigned short* rA = xb + (size_t)((ng + 1) * 64 + 2 * p) * DD + db * 32;
      const unsigned short* rB = rA + DD;
      va0 = *(const uint4*)(rA);      vb0 = *(const uint4*)(rB);
      va1 = *(const uint4*)(rA + 8);  vb1 = *(const uint4*)(rB + 8);
      va2 = *(const uint4*)(rA + 16); vb2 = *(const uint4*)(rB + 16);
      va3 = *(const uint4*)(rA + 24); vb3 = *(const uint4*)(rB + 24);
    }
    #pragma unroll
    for(int kkloc = 0; kkloc < 2; ++kkloc){
      int kk = ng * 2 + kkloc;
      #pragma unroll
      for(int dt = 0; dt < 4; ++dt){
        int d = w * 64 + dt * 16 + m;
        short8 bv = *(const short8*)(xv + d * 128 + ((kkloc * 64 + lg * 16) ^ ((d & 7) << 4)));
        acc[dt] = MFMA(pa[kk], bv, acc[dt]);
      }
    }
  }
  if(l < 32){
    int s4 = (l >> 4) * 4;
    #pragma unroll
    for(int dt = 0; dt < 4; ++dt){
      int d0 = w * 64 + dt * 16;
      #pragma unroll
      for(int j = 0; j < 4; ++j)
        pupd[((size_t)b * 8 + c) * 2048 + (s4 + j) * 256 + d0 + m] = acc[dt][j];
    }
  }
}

// Combine PX partials -> PX/Z ; GRU (gx = PXn@M^T) ; residual MLP ; slots ; LN ; next qk
__global__ __launch_bounds__(1024, 1) void update_kernel(
    const float* __restrict__ pupd, const float* __restrict__ pms,
    float* __restrict__ slots, float* __restrict__ qbuf,
    const short8* __restrict__ mp, const short8* __restrict__ whh,
    const float* __restrict__ bih, const float* __restrict__ bhh,
    const short8* __restrict__ w1p, const float* __restrict__ b1v,
    const short8* __restrict__ w2p, const float* __restrict__ b2v,
    const float* __restrict__ lnsg, const float* __restrict__ lnsb,
    const float* __restrict__ lnmg, const float* __restrict__ lnmb,
    const short8* __restrict__ wqkp,
    float* __restrict__ dout, const int last)
{
  const int b = blockIdx.x, t = threadIdx.x, w = t >> 6, l = t & 63;
  __shared__ unsigned short A1[16 * 256];
  __shared__ unsigned short A2[16 * 256];
  __shared__ unsigned short A3[16 * 512];
  __shared__ float GR[8 * 256], GZ[8 * 256], GXN[8 * 256], GHN[8 * 256];
  __shared__ float SL[8 * 256];
  __shared__ float PMS[128];

  if(t < 128) PMS[t] = pms[(size_t)b * 128 + t];
  __syncthreads();

  const int col = t & 255, sg = t >> 8;
  float upd[2], pv[2];
  #pragma unroll
  for(int ss = 0; ss < 2; ++ss){
    int s = sg * 2 + ss;
    float mx = -1e30f;
    #pragma unroll
    for(int cc = 0; cc < 8; ++cc) mx = fmaxf(mx, PMS[(cc * 8 + s) * 2]);
    float Z = 0.f, u = 0.f;
    #pragma unroll
    for(int cc = 0; cc < 8; ++cc){
      float e = __expf(PMS[(cc * 8 + s) * 2] - mx);
      Z += e * PMS[(cc * 8 + s) * 2 + 1];
      u += e * pupd[((size_t)b * 8 + cc) * 2048 + s * 256 + col];
    }
    upd[ss] = u / Z;
    pv[ss]  = slots[(size_t)b * 2048 + s * 256 + col];
  }
  #pragma unroll
  for(int ss = 0; ss < 2; ++ss){
    int s = sg * 2 + ss;
    int byte = s * 512 + ((col * 2) ^ ((s & 7) << 4));
    *(unsigned short*)((char*)A1 + byte) = f2bf(upd[ss]);
    *(unsigned short*)((char*)A2 + byte) = f2bf(pv[ss]);
  }
  __syncthreads();

  {
    const int mq = l & 15;
    short8 a1f[8], a2f[8];
    #pragma unroll
    for(int kk = 0; kk < 8; ++kk){
      int ab = mq * 512 + (((kk * 64) + ((l >> 4) << 4)) ^ ((mq & 7) << 4));
      a1f[kk] = *(const short8*)((const char*)A1 + ab);
      a2f[kk] = *(const short8*)((const char*)A2 + ab);
    }
    #pragma unroll
    for(int i = 0; i < 3; ++i){
      int et = w + i * 16;
      f32x4 c1 = (f32x4){0,0,0,0}, c2 = (f32x4){0,0,0,0};
      #pragma unroll
      for(int kk = 0; kk < 8; ++kk){
        c1 = MFMA(a1f[kk], mp[((kk * 48 + et) << 6) + l], c1);
        c2 = MFMA(a2f[kk], whh[((kk * 48 + et) << 6) + l], c2);
      }
      int e = et * 16 + (l & 15);
      float xb = bih[e], hb = bhh[e];
      #pragma unroll
      for(int j = 0; j < 4; ++j){
        int s = ((l >> 4) << 2) + j;
        if(s < 8){
          float xx = c1[j] + xb, h = c2[j] + hb;
          if(i == 0)      GR[s * 256 + e      ] = 1.f/(1.f + __expf(-(xx + h)));
          else if(i == 1) GZ[s * 256 + (e-256)] = 1.f/(1.f + __expf(-(xx + h)));
          else { GXN[s * 256 + (e-512)] = xx; GHN[s * 256 + (e-512)] = h; }
        }
      }
    }
  }
  __syncthreads();

  #pragma unroll
  for(int ss = 0; ss < 2; ++ss){
    int s = sg * 2 + ss, idx = s * 256 + col;
    float r = GR[idx], z = GZ[idx], xn = GXN[idx], hn = GHN[idx];
    float nn = tanhf(xn + r * hn);
    SL[idx] = (1.f - z) * nn + z * pv[ss];
  }
  __syncthreads();

  if(w < 8){
    float4 g4 = ((const float4*)lnmg)[l], bb4 = ((const float4*)lnmb)[l];
    int s = w;
    float4 x4 = ((const float4*)(SL + s * 256))[l];
    float s1 = x4.x + x4.y + x4.z + x4.w;
    float s2 = x4.x*x4.x + x4.y*x4.y + x4.z*x4.z + x4.w*x4.w;
    #pragma unroll
    for(int o = 32; o >= 1; o >>= 1){ s1 += __shfl_xor(s1, o); s2 += __shfl_xor(s2, o); }
    float mean = s1 * (1.0f/256.0f);
    float inv  = rsqrtf(s2 * (1.0f/256.0f) - mean*mean + 1e-5f);
    float y0 = (x4.x-mean)*inv*g4.x + bb4.x;
    float y1 = (x4.y-mean)*inv*g4.y + bb4.y;
    float y2 = (x4.z-mean)*inv*g4.z + bb4.z;
    float y3 = (x4.w-mean)*inv*g4.w + bb4.w;
    int byte = s * 512 + ((l * 8) ^ ((s & 7) << 4));
    *(uint2*)((char*)A1 + byte) = make_uint2(pk2(y0,y1), pk2(y2,y3));
  }
  __syncthreads();

  {
    const int mq = l & 15;
    short8 af[8];
    #pragma unroll
    for(int kk = 0; kk < 8; ++kk){
      int ab = mq * 512 + (((kk * 64) + ((l >> 4) << 4)) ^ ((mq & 7) << 4));
      af[kk] = *(const short8*)((const char*)A1 + ab);
    }
    #pragma unroll
    for(int i = 0; i < 2; ++i){
      int et = w + i * 16;
      f32x4 cc = (f32x4){0,0,0,0};
      #pragma unroll
      for(int kk = 0; kk < 8; ++kk) cc = MFMA(af[kk], w1p[((kk * 32 + et) << 6) + l], cc);
      int e = et * 16 + (l & 15);
      float bb = b1v[e];
      #pragma unroll
      for(int j = 0; j < 4; ++j){
        int s = ((l >> 4) << 2) + j;
        if(s < 8){
          float h = fmaxf(cc[j] + bb, 0.f);
          int byte = s * 1024 + ((e * 2) ^ ((s & 7) << 4));
          *(unsigned short*)((char*)A3 + byte) = f2bf(h);
        }
      }
    }
  }
  __syncthreads();

  {
    const int mq = l & 15;
    short8 af[16];
    #pragma unroll
    for(int kk = 0; kk < 16; ++kk){
      int ab = mq * 1024 + (((kk * 64) + ((l >> 4) << 4)) ^ ((mq & 7) << 4));
      af[kk] = *(const short8*)((const char*)A3 + ab);
    }
    {
      int et = w;
      f32x4 cc = (f32x4){0,0,0,0};
      #pragma unroll
      for(int kk = 0; kk < 16; ++kk) cc = MFMA(af[kk], w2p[((kk * 16 + et) << 6) + l], cc);
      int e = et * 16 + (l & 15);
      float bb = b2v[e];
      #pragma unroll
      for(int j = 0; j < 4; ++j){
        int s = ((l >> 4) << 2) + j;
        if(s < 8) GR[s * 256 + e] = SL[s * 256 + e] + cc[j] + bb;
      }
    }
  }
  __syncthreads();

  for(int i = t; i < 2048; i += 1024){
    float v = GR[i];
    slots[(size_t)b * 2048 + i] = v;
    if(last) dout[(size_t)b * 2048 + i] = v;
  }
  if(w < 8){
    float4 g4 = ((const float4*)lnsg)[l], bb4 = ((const float4*)lnsb)[l];
    int s = w;
    float4 x4 = ((const float4*)(GR + s * 256))[l];
    float s1 = x4.x + x4.y + x4.z + x4.w;
    float s2 = x4.x*x4.x + x4.y*x4.y + x4.z*x4.z + x4.w*x4.w;
    #pragma unroll
    for(int o = 32; o >= 1; o >>= 1){ s1 += __shfl_xor(s1, o); s2 += __shfl_xor(s2, o); }
    float mean = s1 * (1.0f/256.0f);
    float inv  = rsqrtf(s2 * (1.0f/256.0f) - mean*mean + 1e-5f);
    float y0 = (x4.x-mean)*inv*g4.x + bb4.x;
    float y1 = (x4.y-mean)*inv*g4.y + bb4.y;
    float y2 = (x4.z-mean)*inv*g4.z + bb4.z;
    float y3 = (x4.w-mean)*inv*g4.w + bb4.w;
    int byte = s * 512 + ((l * 8) ^ ((s & 7) << 4));
    *(uint2*)((char*)A1 + byte) = make_uint2(pk2(y0,y1), pk2(y2,y3));
  }
  __syncthreads();
  {
    const int mq = l & 15;
    short8 af[8];
    #pragma unroll
    for(int kk = 0; kk < 8; ++kk){
      int ab = mq * 512 + (((kk * 64) + ((l >> 4) << 4)) ^ ((mq & 7) << 4));
      af[kk] = *(const short8*)((const char*)A1 + ab);
    }
    {
      int et = w;
      f32x4 cc = (f32x4){0,0,0,0};
      #pragma unroll
      for(int kk = 0; kk < 8; ++kk) cc = MFMA(af[kk], wqkp[((kk * 16 + et) << 6) + l], cc);
      int e = et * 16 + (l & 15);
      #pragma unroll
      for(int j = 0; j < 4; ++j){
        int s = ((l >> 4) << 2) + j;
        if(s < 8) qbuf[(size_t)b * 2048 + s * 256 + e] = cc[j];
      }
    }
  }
}

extern "C" void kernel_launch(void* const* d_in, const int* in_sizes, int n_in,
                              void* d_out, int out_size, void* d_ws, size_t ws_size,
                              hipStream_t stream)
{
  const float* inp   = (const float*)d_in[0];
  const float* noise = (const float*)d_in[1];
  const float* mu    = (const float*)d_in[2];
  const float* lsg   = (const float*)d_in[3];
  const float* lngi  = (const float*)d_in[4];
  const float* lnbi  = (const float*)d_in[5];
  const float* lngs  = (const float*)d_in[6];
  const float* lnbs  = (const float*)d_in[7];
  const float* lngm  = (const float*)d_in[8];
  const float* lnbm  = (const float*)d_in[9];
  const float* Wq    = (const float*)d_in[10];
  const float* Wk    = (const float*)d_in[11];
  const float* Wv    = (const float*)d_in[12];
  const float* Wih   = (const float*)d_in[13];
  const float* Whh   = (const float*)d_in[14];
  const float* bih   = (const float*)d_in[15];
  const float* bhh   = (const float*)d_in[16];
  const float* W1    = (const float*)d_in[17];
  const float* b1    = (const float*)d_in[18];
  const float* W2    = (const float*)d_in[19];
  const float* b2    = (const float*)d_in[20];
  float* dout = (float*)d_out;

  char* ws = (char*)d_ws;
  size_t off = 0;
  unsigned short* x   = (unsigned short*)(ws + off); off += (size_t)BB*NN*DD*2;
  short8* wqkp= (short8*)(ws + off); off += (size_t)256*256*2;
  short8* mp  = (short8*)(ws + off); off += (size_t)768*256*2;
  short8* whhp= (short8*)(ws + off); off += (size_t)768*256*2;
  short8* w1p = (short8*)(ws + off); off += (size_t)512*256*2;
  short8* w2p = (short8*)(ws + off); off += (size_t)256*512*2;
  float* wqkT = (float*)(ws + off);  off += (size_t)256*256*4;
  float* mf32 = (float*)(ws + off);  off += (size_t)768*256*4;
  float* qbuf = (float*)(ws + off);  off += (size_t)512*256*4;
  float* slots= (float*)(ws + off);  off += (size_t)512*256*4;
  float* pupd = (float*)(ws + off);  off += (size_t)64*8*8*256*4;
  float* pms  = (float*)(ws + off);  off += (size_t)64*8*8*2*4;

  pre_kernel<<<1024, 256, 0, stream>>>(Wq, Wk, Wih, Wv, wqkT, mf32);

  PackDesc pd;
  const float* srcs[5] = {wqkT, mf32, Whh, W1, W2};
  unsigned short* dsts[5] = {(unsigned short*)wqkp, (unsigned short*)mp,
                             (unsigned short*)whhp, (unsigned short*)w1p,
                             (unsigned short*)w2p};
  int ets[5] = {16, 48, 48, 32, 16};
  int ks [5] = {256, 256, 256, 256, 512};
  int cum = 0;
  for(int i = 0; i < 5; ++i){
    pd.src[i] = srcs[i]; pd.dst[i] = dsts[i]; pd.ET[i] = ets[i]; pd.K[i] = ks[i];
    pd.blkStart[i] = cum;
    cum += (ets[i] * 16 * ks[i] + 255) / 256;
  }
  pd.blkStart[5] = cum;
  pack_all_kernel<<<cum, 256, 0, stream>>>(pd);

  ln_kernel<<<4096, 256, 0, stream>>>(inp, lngi, lnbi, x);
  init_kernel<<<64, 256, 0, stream>>>(noise, mu, lsg, lngs, lnbs, wqkp, slots, qbuf);

  for(int it = 0; it < 3; ++it){
    attn_kernel<<<512, 256, 0, stream>>>(x, qbuf, pupd, pms);
    update_kernel<<<64, 1024, 0, stream>>>(pupd, pms, slots, qbuf, mp, whhp,
        bih, bhh, w1p, b1, w2p, b2, lngs, lnbs, lngm, lnbm, wqkp, dout, (it == 2) ? 1 : 0);
  }
}

// Round 14
// 342.278 us; speedup vs baseline: 1.4183x; 1.0113x over previous
//
#include <hip/hip_runtime.h>

// Slot attention, MI355X. B=64,N=4096,S=8,D=256,H=512,ITERS=3.
// K,V never materialized (Wqk = scale*Wq^T@Wk, M = W_ih@Wv folded).
// Single-copy x: PV re-reads the QK chunk via an LDS transpose (no xT buffer),
// prefetched loads hide latency; PV staging is WARP-PRIVATE -> no barriers.
#define BB 64
#define NN 4096
#define SS 8
#define DD 256
#define HH 512
#define NCH 8
#define CHK 512
#define LSP 516   // padded row stride (f32) for logits LDS

typedef __attribute__((ext_vector_type(4))) float f32x4;
typedef __attribute__((ext_vector_type(8))) short short8;
typedef __attribute__((ext_vector_type(8))) __bf16 bf16x8;

static __device__ __forceinline__ f32x4 MFMA(short8 a, short8 b, f32x4 c){
  return __builtin_amdgcn_mfma_f32_16x16x32_bf16(
      __builtin_bit_cast(bf16x8, a), __builtin_bit_cast(bf16x8, b), c, 0, 0, 0);
}

static __device__ __forceinline__ unsigned short f2bf(float f){
  unsigned int x = __builtin_bit_cast(unsigned int, f);
  x += 0x7FFFu + ((x >> 16) & 1u);
  return (unsigned short)(x >> 16);
}

static __device__ __forceinline__ unsigned int pk2(float a, float b){
  return (unsigned int)f2bf(a) | ((unsigned int)f2bf(b) << 16);
}

// ---- merged precompute:
//   blk <  256: wqkT[d2][d1] = scale * sum_e Wq[e][d1]*Wk[e][d2]
//   blk >= 256: m[e][c]     = sum_d Wih[e][d]*Wv[d][c]
__global__ __launch_bounds__(256, 4) void pre_kernel(
    const float* __restrict__ Wq, const float* __restrict__ Wk,
    const float* __restrict__ Wih, const float* __restrict__ Wv,
    float* __restrict__ wqkT, float* __restrict__ mf32)
{
  __shared__ float sh[256];
  const int blk = blockIdx.x, t = threadIdx.x;
  if(blk < 256){
    const int d2 = blk;
    sh[t] = Wk[(size_t)t * 256 + d2];
    __syncthreads();
    float acc = 0.f;
    #pragma unroll 8
    for(int e = 0; e < 256; ++e) acc += sh[e] * Wq[(size_t)e * 256 + t];
    wqkT[(size_t)d2 * 256 + t] = acc * 0.0625f;
  } else {
    const int e = blk - 256;
    sh[t] = Wih[(size_t)e * 256 + t];
    __syncthreads();
    float acc = 0.f;
    #pragma unroll 8
    for(int d = 0; d < 256; ++d) acc += sh[d] * Wv[(size_t)d * 256 + t];
    mf32[(size_t)e * 256 + t] = acc;
  }
}

// ---- merged weight pack: W(E=ET*16, K) fp32 row-major -> bf16 MFMA fragments
struct PackDesc {
  const float* src[5];
  unsigned short* dst[5];
  int ET[5];
  int K[5];
  int blkStart[6];
};

__global__ void pack_all_kernel(PackDesc pd){
  int blk = blockIdx.x;
  int seg = 0;
  #pragma unroll
  for(int i = 1; i < 5; ++i) if(blk >= pd.blkStart[i]) seg = i;
  int tid = (blk - pd.blkStart[seg]) * 256 + threadIdx.x;
  int ET = pd.ET[seg], K = pd.K[seg];
  if(tid >= ET * 16 * K) return;
  int i    = tid & 7;
  int lane = (tid >> 3) & 63;
  int rest = tid >> 9;
  int et = rest % ET;
  int kk = rest / ET;
  int row = et * 16 + (lane & 15);
  int col = kk * 32 + ((lane >> 4) << 3) + i;
  pd.dst[seg][tid] = f2bf(pd.src[seg][(size_t)row * K + col]);
}

// LN(inputs) -> x (bf16 row-major). Pure streaming, no LDS.
__global__ __launch_bounds__(256, 4) void ln_kernel(
    const float* __restrict__ inp, const float* __restrict__ g, const float* __restrict__ bta,
    unsigned short* __restrict__ x)
{
  const int t = threadIdx.x, w = t >> 6, l = t & 63;
  const size_t row0 = (size_t)blockIdx.x * 64;
  const int li = l & 15, lg = l >> 4;

  float4 gg[4], bb[4];
  #pragma unroll
  for(int q = 0; q < 4; ++q){
    gg[q] = ((const float4*)g)[li + q * 16];
    bb[q] = ((const float4*)bta)[li + q * 16];
  }
  #pragma unroll
  for(int rr = 0; rr < 4; ++rr){
    int r = w * 16 + rr * 4 + lg;
    const float4* rp = (const float4*)(inp + (row0 + r) * DD);
    float4 xv[4];
    #pragma unroll
    for(int q = 0; q < 4; ++q) xv[q] = rp[li + q * 16];
    float s1 = 0.f, s2 = 0.f;
    #pragma unroll
    for(int q = 0; q < 4; ++q){
      s1 += xv[q].x + xv[q].y + xv[q].z + xv[q].w;
      s2 += xv[q].x*xv[q].x + xv[q].y*xv[q].y + xv[q].z*xv[q].z + xv[q].w*xv[q].w;
    }
    #pragma unroll
    for(int o = 8; o >= 1; o >>= 1){ s1 += __shfl_xor(s1, o); s2 += __shfl_xor(s2, o); }
    float mean = s1 * (1.0f/256.0f);
    float inv  = rsqrtf(s2 * (1.0f/256.0f) - mean*mean + 1e-5f);
    #pragma unroll
    for(int q = 0; q < 4; ++q){
      float y0 = (xv[q].x-mean)*inv*gg[q].x + bb[q].x;
      float y1 = (xv[q].y-mean)*inv*gg[q].y + bb[q].y;
      float y2 = (xv[q].z-mean)*inv*gg[q].z + bb[q].z;
      float y3 = (xv[q].w-mean)*inv*gg[q].w + bb[q].w;
      *(uint2*)((char*)x + (row0 + r) * 512 + q * 128 + li * 8) =
          make_uint2(pk2(y0,y1), pk2(y2,y3));
    }
  }
}

// slots0 = mu + exp(log_sigma)*noise ; qk = LN_slots(slots0) @ Wqk
__global__ __launch_bounds__(256, 1) void init_kernel(
    const float* __restrict__ noise, const float* __restrict__ mu, const float* __restrict__ lsg,
    const float* __restrict__ lng, const float* __restrict__ lnb,
    const short8* __restrict__ wqkp, float* __restrict__ slots, float* __restrict__ qbuf)
{
  const int b = blockIdx.x, t = threadIdx.x, w = t >> 6, l = t & 63;
  __shared__ float SLN[SS * DD];
  __shared__ unsigned short A1[16 * DD];
  float muv = mu[t];
  float sgv = __expf(lsg[t]);
  #pragma unroll
  for(int s = 0; s < SS; ++s){
    float v = muv + sgv * noise[(size_t)b * 2048 + s * 256 + t];
    slots[(size_t)b * 2048 + s * 256 + t] = v;
    SLN[s * 256 + t] = v;
  }
  __syncthreads();
  float4 g4 = ((const float4*)lng)[l], bb4 = ((const float4*)lnb)[l];
  for(int sh = 0; sh < 2; ++sh){
    int s = w * 2 + sh;
    float4 x4 = ((const float4*)(SLN + s * 256))[l];
    float s1 = x4.x + x4.y + x4.z + x4.w;
    float s2 = x4.x*x4.x + x4.y*x4.y + x4.z*x4.z + x4.w*x4.w;
    #pragma unroll
    for(int o = 32; o >= 1; o >>= 1){ s1 += __shfl_xor(s1, o); s2 += __shfl_xor(s2, o); }
    float mean = s1 * (1.0f/256.0f);
    float inv  = rsqrtf(s2 * (1.0f/256.0f) - mean*mean + 1e-5f);
    float y0 = (x4.x-mean)*inv*g4.x + bb4.x;
    float y1 = (x4.y-mean)*inv*g4.y + bb4.y;
    float y2 = (x4.z-mean)*inv*g4.z + bb4.z;
    float y3 = (x4.w-mean)*inv*g4.w + bb4.w;
    int byte = s * 512 + ((l * 8) ^ ((s & 7) << 4));
    *(uint2*)((char*)A1 + byte) = make_uint2(pk2(y0,y1), pk2(y2,y3));
  }
  __syncthreads();
  const int m = l & 15;
  short8 af[8];
  #pragma unroll
  for(int kk = 0; kk < 8; ++kk){
    int ab = m * 512 + (((kk * 64) + ((l >> 4) << 4)) ^ ((m & 7) << 4));
    af[kk] = *(const short8*)((const char*)A1 + ab);
  }
  #pragma unroll
  for(int i = 0; i < 4; ++i){
    int et = w + i * 4;
    f32x4 c = (f32x4){0,0,0,0};
    #pragma unroll
    for(int kk = 0; kk < 8; ++kk) c = MFMA(af[kk], wqkp[((kk * 16 + et) << 6) + l], c);
    int e = et * 16 + (l & 15);
    #pragma unroll
    for(int j = 0; j < 4; ++j){
      int s = ((l >> 4) << 2) + j;
      if(s < 8) qbuf[(size_t)b * 2048 + s * 256 + e] = c[j];
    }
  }
}

// MFMA flash partials: logits = qk@x^T (B=x row-major), softmax,
// PX = P@x via LDS transpose. PV staging is warp-private (warp w stages and
// consumes exactly d-range [64w, 64w+64)) -> zero barriers in the PV loop;
// per-wave in-order DS ops guarantee write->read visibility.
__global__ __launch_bounds__(256, 3) void attn_kernel(
    const unsigned short* __restrict__ x_, const float* __restrict__ qbuf,
    float* __restrict__ pupd, float* __restrict__ pms)
{
  const int blk = blockIdx.x;
  const int b = blk >> 3, c = blk & 7;
  const int t = threadIdx.x, w = t >> 6, l = t & 63;
  __shared__ float ls[8 * LSP];            // 16.5 KB exp(logits)
  __shared__ __align__(16) char xv[256 * 128];  // 32 KB transposed sub-chunk [256d][64n]

  const int m = l & 15, lg = l >> 4;
  short8 aq[8];
  #pragma unroll
  for(int kk = 0; kk < 8; ++kk){
    if(m < 8){
      const float* qp = qbuf + (size_t)b * 2048 + m * 256 + kk * 32 + (lg << 3);
      float4 qa = *(const float4*)qp;
      float4 qb = *(const float4*)(qp + 4);
      int4 pv = make_int4((int)pk2(qa.x,qa.y), (int)pk2(qa.z,qa.w),
                          (int)pk2(qb.x,qb.y), (int)pk2(qb.z,qb.w));
      aq[kk] = __builtin_bit_cast(short8, pv);
    } else {
      aq[kk] = (short8){0,0,0,0,0,0,0,0};
    }
  }

  const unsigned short* xb = x_ + ((size_t)b * NN + (size_t)c * CHK) * DD;
  #pragma unroll
  for(int nt = 0; nt < 8; ++nt){
    int nb = w * 128 + nt * 16;
    f32x4 acc = (f32x4){0,0,0,0};
    #pragma unroll
    for(int kk = 0; kk < 8; ++kk){
      short8 bk = *(const short8*)(xb + (size_t)(nb + m) * DD + kk * 32 + ((l >> 4) << 3));
      acc = MFMA(aq[kk], bk, acc);
    }
    if(l < 32){
      int s4 = (l >> 4) * 4;
      #pragma unroll
      for(int j = 0; j < 4; ++j) ls[(s4 + j) * LSP + nb + m] = acc[j];
    }
  }
  __syncthreads();

  for(int sh = 0; sh < 2; ++sh){
    int s = w * 2 + sh;
    float* base = ls + s * LSP;
    float4 v0 = *(float4*)(base + l * 4);
    float4 v1 = *(float4*)(base + 256 + l * 4);
    float mx = fmaxf(fmaxf(fmaxf(v0.x,v0.y),fmaxf(v0.z,v0.w)),
                     fmaxf(fmaxf(v1.x,v1.y),fmaxf(v1.z,v1.w)));
    #pragma unroll
    for(int o = 32; o >= 1; o >>= 1) mx = fmaxf(mx, __shfl_xor(mx, o));
    float e0 = __expf(v0.x-mx), e1 = __expf(v0.y-mx), e2 = __expf(v0.z-mx), e3 = __expf(v0.w-mx);
    float e4 = __expf(v1.x-mx), e5 = __expf(v1.y-mx), e6 = __expf(v1.z-mx), e7 = __expf(v1.w-mx);
    float sm = e0+e1+e2+e3+e4+e5+e6+e7;
    #pragma unroll
    for(int o = 32; o >= 1; o >>= 1) sm += __shfl_xor(sm, o);
    *(float4*)(base + l * 4)       = make_float4(e0,e1,e2,e3);
    *(float4*)(base + 256 + l * 4) = make_float4(e4,e5,e6,e7);
    if(l == 0){
      pms[(((size_t)b * 8 + c) * 8 + s) * 2    ] = mx;
      pms[(((size_t)b * 8 + c) * 8 + s) * 2 + 1] = sm;
    }
  }
  __syncthreads();

  short8 pa[16];
  #pragma unroll
  for(int kk = 0; kk < 16; ++kk){
    if(m < 8){
      const float* pp = ls + m * LSP + kk * 32 + ((l >> 4) << 3);
      int4 pv = make_int4((int)pk2(pp[0],pp[1]), (int)pk2(pp[2],pp[3]),
                          (int)pk2(pp[4],pp[5]), (int)pk2(pp[6],pp[7]));
      pa[kk] = __builtin_bit_cast(short8, pv);
    } else {
      pa[kk] = (short8){0,0,0,0,0,0,0,0};
    }
  }

  // PV: loop 64-n sub-chunks; warp-private staging (no barriers).
  f32x4 acc[4];
  #pragma unroll
  for(int dt = 0; dt < 4; ++dt) acc[dt] = (f32x4){0,0,0,0};
  const int p = t & 31, db = t >> 5;   // n-pair 0..31, d-block (2w / 2w+1)

  uint4 va0, va1, va2, va3, vb0, vb1, vb2, vb3;
  {
    const unsigned short* rA = xb + (size_t)(2 * p) * DD + db * 32;
    const unsigned short* rB = rA + DD;
    va0 = *(const uint4*)(rA);      vb0 = *(const uint4*)(rB);
    va1 = *(const uint4*)(rA + 8);  vb1 = *(const uint4*)(rB + 8);
    va2 = *(const uint4*)(rA + 16); vb2 = *(const uint4*)(rB + 16);
    va3 = *(const uint4*)(rA + 24); vb3 = *(const uint4*)(rB + 24);
  }

  for(int ng = 0; ng < 8; ++ng){
    {
      uint4 VA[4] = {va0, va1, va2, va3};
      uint4 VB[4] = {vb0, vb1, vb2, vb3};
      #pragma unroll
      for(int q = 0; q < 4; ++q){
        unsigned int wa[4] = {VA[q].x, VA[q].y, VA[q].z, VA[q].w};
        unsigned int wb[4] = {VB[q].x, VB[q].y, VB[q].z, VB[q].w};
        #pragma unroll
        for(int h = 0; h < 4; ++h){
          int d0 = db * 32 + q * 8 + h * 2;
          unsigned int a = wa[h], bv = wb[h];
          unsigned int v0 = (a & 0xFFFFu) | (bv << 16);
          unsigned int v1 = (a >> 16) | (bv & 0xFFFF0000u);
          *(unsigned int*)(xv + d0 * 128 + ((p * 4) ^ ((d0 & 7) << 4))) = v0;
          int d1 = d0 + 1;
          *(unsigned int*)(xv + d1 * 128 + ((p * 4) ^ ((d1 & 7) << 4))) = v1;
        }
      }
    }
    if(ng < 7){
      const unsigned short* rA = xb + (size_t)((ng + 1) * 64 + 2 * p) * DD + db * 32;
      const unsigned short* rB = rA + DD;
      va0 = *(const uint4*)(rA);      vb0 = *(const uint4*)(rB);
      va1 = *(const uint4*)(rA + 8);  vb1 = *(const uint4*)(rB + 8);
      va2 = *(const uint4*)(rA + 16); vb2 = *(const uint4*)(rB + 16);
      va3 = *(const uint4*)(rA + 24); vb3 = *(const uint4*)(rB + 24);
    }
    #pragma unroll
    for(int kkloc = 0; kkloc < 2; ++kkloc){
      int kk = ng * 2 + kkloc;
      #pragma unroll
      for(int dt = 0; dt < 4; ++dt){
        int d = w * 64 + dt * 16 + m;
        short8 bv = *(const short8*)(xv + d * 128 + ((kkloc * 64 + lg * 16) ^ ((d & 7) << 4)));
        acc[dt] = MFMA(pa[kk], bv, acc[dt]);
      }
    }
  }
  if(l < 32){
    int s4 = (l >> 4) * 4;
    #pragma unroll
    for(int dt = 0; dt < 4; ++dt){
      int d0 = w * 64 + dt * 16;
      #pragma unroll
      for(int j = 0; j < 4; ++j)
        pupd[((size_t)b * 8 + c) * 2048 + (s4 + j) * 256 + d0 + m] = acc[dt][j];
    }
  }
}

// Combine PX partials -> PX/Z ; GRU (gx = PXn@M^T) ; residual MLP ; slots ; LN ; next qk
__global__ __launch_bounds__(1024, 1) void update_kernel(
    const float* __restrict__ pupd, const float* __restrict__ pms,
    float* __restrict__ slots, float* __restrict__ qbuf,
    const short8* __restrict__ mp, const short8* __restrict__ whh,
    const float* __restrict__ bih, const float* __restrict__ bhh,
    const short8* __restrict__ w1p, const float* __restrict__ b1v,
    const short8* __restrict__ w2p, const float* __restrict__ b2v,
    const float* __restrict__ lnsg, const float* __restrict__ lnsb,
    const float* __restrict__ lnmg, const float* __restrict__ lnmb,
    const short8* __restrict__ wqkp,
    float* __restrict__ dout, const int last)
{
  const int b = blockIdx.x, t = threadIdx.x, w = t >> 6, l = t & 63;
  __shared__ unsigned short A1[16 * 256];
  __shared__ unsigned short A2[16 * 256];
  __shared__ unsigned short A3[16 * 512];
  __shared__ float GR[8 * 256], GZ[8 * 256], GXN[8 * 256], GHN[8 * 256];
  __shared__ float SL[8 * 256];
  __shared__ float PMS[128];

  if(t < 128) PMS[t] = pms[(size_t)b * 128 + t];
  __syncthreads();

  const int col = t & 255, sg = t >> 8;
  float upd[2], pv[2];
  #pragma unroll
  for(int ss = 0; ss < 2; ++ss){
    int s = sg * 2 + ss;
    float mx = -1e30f;
    #pragma unroll
    for(int cc = 0; cc < 8; ++cc) mx = fmaxf(mx, PMS[(cc * 8 + s) * 2]);
    float Z = 0.f, u = 0.f;
    #pragma unroll
    for(int cc = 0; cc < 8; ++cc){
      float e = __expf(PMS[(cc * 8 + s) * 2] - mx);
      Z += e * PMS[(cc * 8 + s) * 2 + 1];
      u += e * pupd[((size_t)b * 8 + cc) * 2048 + s * 256 + col];
    }
    upd[ss] = u / Z;
    pv[ss]  = slots[(size_t)b * 2048 + s * 256 + col];
  }
  #pragma unroll
  for(int ss = 0; ss < 2; ++ss){
    int s = sg * 2 + ss;
    int byte = s * 512 + ((col * 2) ^ ((s & 7) << 4));
    *(unsigned short*)((char*)A1 + byte) = f2bf(upd[ss]);
    *(unsigned short*)((char*)A2 + byte) = f2bf(pv[ss]);
  }
  __syncthreads();

  {
    const int mq = l & 15;
    short8 a1f[8], a2f[8];
    #pragma unroll
    for(int kk = 0; kk < 8; ++kk){
      int ab = mq * 512 + (((kk * 64) + ((l >> 4) << 4)) ^ ((mq & 7) << 4));
      a1f[kk] = *(const short8*)((const char*)A1 + ab);
      a2f[kk] = *(const short8*)((const char*)A2 + ab);
    }
    #pragma unroll
    for(int i = 0; i < 3; ++i){
      int et = w + i * 16;
      f32x4 c1 = (f32x4){0,0,0,0}, c2 = (f32x4){0,0,0,0};
      #pragma unroll
      for(int kk = 0; kk < 8; ++kk){
        c1 = MFMA(a1f[kk], mp[((kk * 48 + et) << 6) + l], c1);
        c2 = MFMA(a2f[kk], whh[((kk * 48 + et) << 6) + l], c2);
      }
      int e = et * 16 + (l & 15);
      float xb = bih[e], hb = bhh[e];
      #pragma unroll
      for(int j = 0; j < 4; ++j){
        int s = ((l >> 4) << 2) + j;
        if(s < 8){
          float xx = c1[j] + xb, h = c2[j] + hb;
          if(i == 0)      GR[s * 256 + e      ] = 1.f/(1.f + __expf(-(xx + h)));
          else if(i == 1) GZ[s * 256 + (e-256)] = 1.f/(1.f + __expf(-(xx + h)));
          else { GXN[s * 256 + (e-512)] = xx; GHN[s * 256 + (e-512)] = h; }
        }
      }
    }
  }
  __syncthreads();

  #pragma unroll
  for(int ss = 0; ss < 2; ++ss){
    int s = sg * 2 + ss, idx = s * 256 + col;
    float r = GR[idx], z = GZ[idx], xn = GXN[idx], hn = GHN[idx];
    float nn = tanhf(xn + r * hn);
    SL[idx] = (1.f - z) * nn + z * pv[ss];
  }
  __syncthreads();

  if(w < 8){
    float4 g4 = ((const float4*)lnmg)[l], bb4 = ((const float4*)lnmb)[l];
    int s = w;
    float4 x4 = ((const float4*)(SL + s * 256))[l];
    float s1 = x4.x + x4.y + x4.z + x4.w;
    float s2 = x4.x*x4.x + x4.y*x4.y + x4.z*x4.z + x4.w*x4.w;
    #pragma unroll
    for(int o = 32; o >= 1; o >>= 1){ s1 += __shfl_xor(s1, o); s2 += __shfl_xor(s2, o); }
    float mean = s1 * (1.0f/256.0f);
    float inv  = rsqrtf(s2 * (1.0f/256.0f) - mean*mean + 1e-5f);
    float y0 = (x4.x-mean)*inv*g4.x + bb4.x;
    float y1 = (x4.y-mean)*inv*g4.y + bb4.y;
    float y2 = (x4.z-mean)*inv*g4.z + bb4.z;
    float y3 = (x4.w-mean)*inv*g4.w + bb4.w;
    int byte = s * 512 + ((l * 8) ^ ((s & 7) << 4));
    *(uint2*)((char*)A1 + byte) = make_uint2(pk2(y0,y1), pk2(y2,y3));
  }
  __syncthreads();

  {
    const int mq = l & 15;
    short8 af[8];
    #pragma unroll
    for(int kk = 0; kk < 8; ++kk){
      int ab = mq * 512 + (((kk * 64) + ((l >> 4) << 4)) ^ ((mq & 7) << 4));
      af[kk] = *(const short8*)((const char*)A1 + ab);
    }
    #pragma unroll
    for(int i = 0; i < 2; ++i){
      int et = w + i * 16;
      f32x4 cc = (f32x4){0,0,0,0};
      #pragma unroll
      for(int kk = 0; kk < 8; ++kk) cc = MFMA(af[kk], w1p[((kk * 32 + et) << 6) + l], cc);
      int e = et * 16 + (l & 15);
      float bb = b1v[e];
      #pragma unroll
      for(int j = 0; j < 4; ++j){
        int s = ((l >> 4) << 2) + j;
        if(s < 8){
          float h = fmaxf(cc[j] + bb, 0.f);
          int byte = s * 1024 + ((e * 2) ^ ((s & 7) << 4));
          *(unsigned short*)((char*)A3 + byte) = f2bf(h);
        }
      }
    }
  }
  __syncthreads();

  {
    const int mq = l & 15;
    short8 af[16];
    #pragma unroll
    for(int kk = 0; kk < 16; ++kk){
      int ab = mq * 1024 + (((kk * 64) + ((l >> 4) << 4)) ^ ((mq & 7) << 4));
      af[kk] = *(const short8*)((const char*)A3 + ab);
    }
    {
      int et = w;
      f32x4 cc = (f32x4){0,0,0,0};
      #pragma unroll
      for(int kk = 0; kk < 16; ++kk) cc = MFMA(af[kk], w2p[((kk * 16 + et) << 6) + l], cc);
      int e = et * 16 + (l & 15);
      float bb = b2v[e];
      #pragma unroll
      for(int j = 0; j < 4; ++j){
        int s = ((l >> 4) << 2) + j;
        if(s < 8) GR[s * 256 + e] = SL[s * 256 + e] + cc[j] + bb;
      }
    }
  }
  __syncthreads();

  for(int i = t; i < 2048; i += 1024){
    float v = GR[i];
    slots[(size_t)b * 2048 + i] = v;
    if(last) dout[(size_t)b * 2048 + i] = v;
  }
  if(w < 8){
    float4 g4 = ((const float4*)lnsg)[l], bb4 = ((const float4*)lnsb)[l];
    int s = w;
    float4 x4 = ((const float4*)(GR + s * 256))[l];
    float s1 = x4.x + x4.y + x4.z + x4.w;
    float s2 = x4.x*x4.x + x4.y*x4.y + x4.z*x4.z + x4.w*x4.w;
    #pragma unroll
    for(int o = 32; o >= 1; o >>= 1){ s1 += __shfl_xor(s1, o); s2 += __shfl_xor(s2, o); }
    float mean = s1 * (1.0f/256.0f);
    float inv  = rsqrtf(s2 * (1.0f/256.0f) - mean*mean + 1e-5f);
    float y0 = (x4.x-mean)*inv*g4.x + bb4.x;
    float y1 = (x4.y-mean)*inv*g4.y + bb4.y;
    float y2 = (x4.z-mean)*inv*g4.z + bb4.z;
    float y3 = (x4.w-mean)*inv*g4.w + bb4.w;
    int byte = s * 512 + ((l * 8) ^ ((s & 7) << 4));
    *(uint2*)((char*)A1 + byte) = make_uint2(pk2(y0,y1), pk2(y2,y3));
  }
  __syncthreads();
  {
    const int mq = l & 15;
    short8 af[8];
    #pragma unroll
    for(int kk = 0; kk < 8; ++kk){
      int ab = mq * 512 + (((kk * 64) + ((l >> 4) << 4)) ^ ((mq & 7) << 4));
      af[kk] = *(const short8*)((const char*)A1 + ab);
    }
    {
      int et = w;
      f32x4 cc = (f32x4){0,0,0,0};
      #pragma unroll
      for(int kk = 0; kk < 8; ++kk) cc = MFMA(af[kk], wqkp[((kk * 16 + et) << 6) + l], cc);
      int e = et * 16 + (l & 15);
      #pragma unroll
      for(int j = 0; j < 4; ++j){
        int s = ((l >> 4) << 2) + j;
        if(s < 8) qbuf[(size_t)b * 2048 + s * 256 + e] = cc[j];
      }
    }
  }
}

extern "C" void kernel_launch(void* const* d_in, const int* in_sizes, int n_in,
                              void* d_out, int out_size, void* d_ws, size_t ws_size,
                              hipStream_t stream)
{
  const float* inp   = (const float*)d_in[0];
  const float* noise = (const float*)d_in[1];
  const float* mu    = (const float*)d_in[2];
  const float* lsg   = (const float*)d_in[3];
  const float* lngi  = (const float*)d_in[4];
  const float* lnbi  = (const float*)d_in[5];
  const float* lngs  = (const float*)d_in[6];
  const float* lnbs  = (const float*)d_in[7];
  const float* lngm  = (const float*)d_in[8];
  const float* lnbm  = (const float*)d_in[9];
  const float* Wq    = (const float*)d_in[10];
  const float* Wk    = (const float*)d_in[11];
  const float* Wv    = (const float*)d_in[12];
  const float* Wih   = (const float*)d_in[13];
  const float* Whh   = (const float*)d_in[14];
  const float* bih   = (const float*)d_in[15];
  const float* bhh   = (const float*)d_in[16];
  const float* W1    = (const float*)d_in[17];
  const float* b1    = (const float*)d_in[18];
  const float* W2    = (const float*)d_in[19];
  const float* b2    = (const float*)d_in[20];
  float* dout = (float*)d_out;

  char* ws = (char*)d_ws;
  size_t off = 0;
  unsigned short* x   = (unsigned short*)(ws + off); off += (size_t)BB*NN*DD*2;
  short8* wqkp= (short8*)(ws + off); off += (size_t)256*256*2;
  short8* mp  = (short8*)(ws + off); off += (size_t)768*256*2;
  short8* whhp= (short8*)(ws + off); off += (size_t)768*256*2;
  short8* w1p = (short8*)(ws + off); off += (size_t)512*256*2;
  short8* w2p = (short8*)(ws + off); off += (size_t)256*512*2;
  float* wqkT = (float*)(ws + off);  off += (size_t)256*256*4;
  float* mf32 = (float*)(ws + off);  off += (size_t)768*256*4;
  float* qbuf = (float*)(ws + off);  off += (size_t)512*256*4;
  float* slots= (float*)(ws + off);  off += (size_t)512*256*4;
  float* pupd = (float*)(ws + off);  off += (size_t)64*8*8*256*4;
  float* pms  = (float*)(ws + off);  off += (size_t)64*8*8*2*4;

  pre_kernel<<<1024, 256, 0, stream>>>(Wq, Wk, Wih, Wv, wqkT, mf32);

  PackDesc pd;
  const float* srcs[5] = {wqkT, mf32, Whh, W1, W2};
  unsigned short* dsts[5] = {(unsigned short*)wqkp, (unsigned short*)mp,
                             (unsigned short*)whhp, (unsigned short*)w1p,
                             (unsigned short*)w2p};
  int ets[5] = {16, 48, 48, 32, 16};
  int ks [5] = {256, 256, 256, 256, 512};
  int cum = 0;
  for(int i = 0; i < 5; ++i){
    pd.src[i] = srcs[i]; pd.dst[i] = dsts[i]; pd.ET[i] = ets[i]; pd.K[i] = ks[i];
    pd.blkStart[i] = cum;
    cum += (ets[i] * 16 * ks[i] + 255) / 256;
  }
  pd.blkStart[5] = cum;
  pack_all_kernel<<<cum, 256, 0, stream>>>(pd);

  ln_kernel<<<4096, 256, 0, stream>>>(inp, lngi, lnbi, x);
  init_kernel<<<64, 256, 0, stream>>>(noise, mu, lsg, lngs, lnbs, wqkp, slots, qbuf);

  for(int it = 0; it < 3; ++it){
    attn_kernel<<<512, 256, 0, stream>>>(x, qbuf, pupd, pms);
    update_kernel<<<64, 1024, 0, stream>>>(pupd, pms, slots, qbuf, mp, whhp,
        bih, bhh, w1p, b1, w2p, b2, lngs, lnbs, lngm, lnbm, wqkp, dout, (it == 2) ? 1 : 0);
  }
}

// Round 15
// 337.648 us; speedup vs baseline: 1.4378x; 1.0137x over previous
//
#include <hip/hip_runtime.h>

// Slot attention, MI355X. B=64,N=4096,S=8,D=256,H=512,ITERS=3.
// K,V never materialized (Wqk = scale*Wq^T@Wk, M = W_ih@Wv folded).
// attn: 256-row chunks (1024 blocks), ls/xv aliased in one 32KB LDS arena,
// warp-private PV staging with prefetch, setprio around PV MFMAs.
#define BB 64
#define NN 4096
#define SS 8
#define DD 256
#define HH 512
#define NCH 16
#define CHK 256
#define LSP2 260  // padded row stride (f32) for logits LDS

typedef __attribute__((ext_vector_type(4))) float f32x4;
typedef __attribute__((ext_vector_type(8))) short short8;
typedef __attribute__((ext_vector_type(8))) __bf16 bf16x8;

static __device__ __forceinline__ f32x4 MFMA(short8 a, short8 b, f32x4 c){
  return __builtin_amdgcn_mfma_f32_16x16x32_bf16(
      __builtin_bit_cast(bf16x8, a), __builtin_bit_cast(bf16x8, b), c, 0, 0, 0);
}

static __device__ __forceinline__ unsigned short f2bf(float f){
  unsigned int x = __builtin_bit_cast(unsigned int, f);
  x += 0x7FFFu + ((x >> 16) & 1u);
  return (unsigned short)(x >> 16);
}

static __device__ __forceinline__ unsigned int pk2(float a, float b){
  return (unsigned int)f2bf(a) | ((unsigned int)f2bf(b) << 16);
}

// ---- merged precompute:
//   blk <  256: wqkT[d2][d1] = scale * sum_e Wq[e][d1]*Wk[e][d2]
//   blk >= 256: m[e][c]     = sum_d Wih[e][d]*Wv[d][c]
__global__ __launch_bounds__(256, 4) void pre_kernel(
    const float* __restrict__ Wq, const float* __restrict__ Wk,
    const float* __restrict__ Wih, const float* __restrict__ Wv,
    float* __restrict__ wqkT, float* __restrict__ mf32)
{
  __shared__ float sh[256];
  const int blk = blockIdx.x, t = threadIdx.x;
  if(blk < 256){
    const int d2 = blk;
    sh[t] = Wk[(size_t)t * 256 + d2];
    __syncthreads();
    float acc = 0.f;
    #pragma unroll 8
    for(int e = 0; e < 256; ++e) acc += sh[e] * Wq[(size_t)e * 256 + t];
    wqkT[(size_t)d2 * 256 + t] = acc * 0.0625f;
  } else {
    const int e = blk - 256;
    sh[t] = Wih[(size_t)e * 256 + t];
    __syncthreads();
    float acc = 0.f;
    #pragma unroll 8
    for(int d = 0; d < 256; ++d) acc += sh[d] * Wv[(size_t)d * 256 + t];
    mf32[(size_t)e * 256 + t] = acc;
  }
}

// ---- merged weight pack: W(E=ET*16, K) fp32 row-major -> bf16 MFMA fragments
struct PackDesc {
  const float* src[5];
  unsigned short* dst[5];
  int ET[5];
  int K[5];
  int blkStart[6];
};

__global__ void pack_all_kernel(PackDesc pd){
  int blk = blockIdx.x;
  int seg = 0;
  #pragma unroll
  for(int i = 1; i < 5; ++i) if(blk >= pd.blkStart[i]) seg = i;
  int tid = (blk - pd.blkStart[seg]) * 256 + threadIdx.x;
  int ET = pd.ET[seg], K = pd.K[seg];
  if(tid >= ET * 16 * K) return;
  int i    = tid & 7;
  int lane = (tid >> 3) & 63;
  int rest = tid >> 9;
  int et = rest % ET;
  int kk = rest / ET;
  int row = et * 16 + (lane & 15);
  int col = kk * 32 + ((lane >> 4) << 3) + i;
  pd.dst[seg][tid] = f2bf(pd.src[seg][(size_t)row * K + col]);
}

// LN(inputs) -> x (bf16 row-major). Pure streaming, no LDS.
__global__ __launch_bounds__(256, 4) void ln_kernel(
    const float* __restrict__ inp, const float* __restrict__ g, const float* __restrict__ bta,
    unsigned short* __restrict__ x)
{
  const int t = threadIdx.x, w = t >> 6, l = t & 63;
  const size_t row0 = (size_t)blockIdx.x * 64;
  const int li = l & 15, lg = l >> 4;

  float4 gg[4], bb[4];
  #pragma unroll
  for(int q = 0; q < 4; ++q){
    gg[q] = ((const float4*)g)[li + q * 16];
    bb[q] = ((const float4*)bta)[li + q * 16];
  }
  #pragma unroll
  for(int rr = 0; rr < 4; ++rr){
    int r = w * 16 + rr * 4 + lg;
    const float4* rp = (const float4*)(inp + (row0 + r) * DD);
    float4 xv[4];
    #pragma unroll
    for(int q = 0; q < 4; ++q) xv[q] = rp[li + q * 16];
    float s1 = 0.f, s2 = 0.f;
    #pragma unroll
    for(int q = 0; q < 4; ++q){
      s1 += xv[q].x + xv[q].y + xv[q].z + xv[q].w;
      s2 += xv[q].x*xv[q].x + xv[q].y*xv[q].y + xv[q].z*xv[q].z + xv[q].w*xv[q].w;
    }
    #pragma unroll
    for(int o = 8; o >= 1; o >>= 1){ s1 += __shfl_xor(s1, o); s2 += __shfl_xor(s2, o); }
    float mean = s1 * (1.0f/256.0f);
    float inv  = rsqrtf(s2 * (1.0f/256.0f) - mean*mean + 1e-5f);
    #pragma unroll
    for(int q = 0; q < 4; ++q){
      float y0 = (xv[q].x-mean)*inv*gg[q].x + bb[q].x;
      float y1 = (xv[q].y-mean)*inv*gg[q].y + bb[q].y;
      float y2 = (xv[q].z-mean)*inv*gg[q].z + bb[q].z;
      float y3 = (xv[q].w-mean)*inv*gg[q].w + bb[q].w;
      *(uint2*)((char*)x + (row0 + r) * 512 + q * 128 + li * 8) =
          make_uint2(pk2(y0,y1), pk2(y2,y3));
    }
  }
}

// slots0 = mu + exp(log_sigma)*noise ; qk = LN_slots(slots0) @ Wqk
__global__ __launch_bounds__(256, 1) void init_kernel(
    const float* __restrict__ noise, const float* __restrict__ mu, const float* __restrict__ lsg,
    const float* __restrict__ lng, const float* __restrict__ lnb,
    const short8* __restrict__ wqkp, float* __restrict__ slots, float* __restrict__ qbuf)
{
  const int b = blockIdx.x, t = threadIdx.x, w = t >> 6, l = t & 63;
  __shared__ float SLN[SS * DD];
  __shared__ unsigned short A1[16 * DD];
  float muv = mu[t];
  float sgv = __expf(lsg[t]);
  #pragma unroll
  for(int s = 0; s < SS; ++s){
    float v = muv + sgv * noise[(size_t)b * 2048 + s * 256 + t];
    slots[(size_t)b * 2048 + s * 256 + t] = v;
    SLN[s * 256 + t] = v;
  }
  __syncthreads();
  float4 g4 = ((const float4*)lng)[l], bb4 = ((const float4*)lnb)[l];
  for(int sh = 0; sh < 2; ++sh){
    int s = w * 2 + sh;
    float4 x4 = ((const float4*)(SLN + s * 256))[l];
    float s1 = x4.x + x4.y + x4.z + x4.w;
    float s2 = x4.x*x4.x + x4.y*x4.y + x4.z*x4.z + x4.w*x4.w;
    #pragma unroll
    for(int o = 32; o >= 1; o >>= 1){ s1 += __shfl_xor(s1, o); s2 += __shfl_xor(s2, o); }
    float mean = s1 * (1.0f/256.0f);
    float inv  = rsqrtf(s2 * (1.0f/256.0f) - mean*mean + 1e-5f);
    float y0 = (x4.x-mean)*inv*g4.x + bb4.x;
    float y1 = (x4.y-mean)*inv*g4.y + bb4.y;
    float y2 = (x4.z-mean)*inv*g4.z + bb4.z;
    float y3 = (x4.w-mean)*inv*g4.w + bb4.w;
    int byte = s * 512 + ((l * 8) ^ ((s & 7) << 4));
    *(uint2*)((char*)A1 + byte) = make_uint2(pk2(y0,y1), pk2(y2,y3));
  }
  __syncthreads();
  const int m = l & 15;
  short8 af[8];
  #pragma unroll
  for(int kk = 0; kk < 8; ++kk){
    int ab = m * 512 + (((kk * 64) + ((l >> 4) << 4)) ^ ((m & 7) << 4));
    af[kk] = *(const short8*)((const char*)A1 + ab);
  }
  #pragma unroll
  for(int i = 0; i < 4; ++i){
    int et = w + i * 4;
    f32x4 c = (f32x4){0,0,0,0};
    #pragma unroll
    for(int kk = 0; kk < 8; ++kk) c = MFMA(af[kk], wqkp[((kk * 16 + et) << 6) + l], c);
    int e = et * 16 + (l & 15);
    #pragma unroll
    for(int j = 0; j < 4; ++j){
      int s = ((l >> 4) << 2) + j;
      if(s < 8) qbuf[(size_t)b * 2048 + s * 256 + e] = c[j];
    }
  }
}

// MFMA flash partials over 256-row chunks: logits = qk@x^T, softmax, PX = P@x.
// ls (logits, 8.3KB) and xv (transpose tile, 32KB) alias one arena: pa fragments
// are fully in registers before xv overwrites ls (single barrier guards it).
__global__ __launch_bounds__(256, 3) void attn_kernel(
    const unsigned short* __restrict__ x_, const float* __restrict__ qbuf,
    float* __restrict__ pupd, float* __restrict__ pms)
{
  const int blk = blockIdx.x;
  const int b = blk >> 4, c = blk & 15;
  const int t = threadIdx.x, w = t >> 6, l = t & 63;
  __shared__ __align__(16) char SMEM[32768];
  float* ls = (float*)SMEM;          // 8 * 260 * 4 = 8320 B
  char*  xv = SMEM;                  // 256d * 128B = 32768 B (aliases ls)

  const int m = l & 15, lg = l >> 4;
  short8 aq[8];
  #pragma unroll
  for(int kk = 0; kk < 8; ++kk){
    if(m < 8){
      const float* qp = qbuf + (size_t)b * 2048 + m * 256 + kk * 32 + (lg << 3);
      float4 qa = *(const float4*)qp;
      float4 qb = *(const float4*)(qp + 4);
      int4 pv = make_int4((int)pk2(qa.x,qa.y), (int)pk2(qa.z,qa.w),
                          (int)pk2(qb.x,qb.y), (int)pk2(qb.z,qb.w));
      aq[kk] = __builtin_bit_cast(short8, pv);
    } else {
      aq[kk] = (short8){0,0,0,0,0,0,0,0};
    }
  }

  const unsigned short* xb = x_ + ((size_t)b * NN + (size_t)c * CHK) * DD;
  // QK: warp w covers n-tiles w*64 .. w*64+63
  #pragma unroll
  for(int nt = 0; nt < 4; ++nt){
    int nb = w * 64 + nt * 16;
    f32x4 acc = (f32x4){0,0,0,0};
    #pragma unroll
    for(int kk = 0; kk < 8; ++kk){
      short8 bk = *(const short8*)(xb + (size_t)(nb + m) * DD + kk * 32 + (lg << 3));
      acc = MFMA(aq[kk], bk, acc);
    }
    if(l < 32){
      int s4 = lg * 4;
      #pragma unroll
      for(int j = 0; j < 4; ++j) ls[(s4 + j) * LSP2 + nb + m] = acc[j];
    }
  }
  __syncthreads();

  // softmax over the 256-chunk per slot (warp w handles slots 2w, 2w+1)
  for(int sh = 0; sh < 2; ++sh){
    int s = w * 2 + sh;
    float* base = ls + s * LSP2;
    float4 v0 = *(float4*)(base + l * 4);
    float mx = fmaxf(fmaxf(v0.x,v0.y),fmaxf(v0.z,v0.w));
    #pragma unroll
    for(int o = 32; o >= 1; o >>= 1) mx = fmaxf(mx, __shfl_xor(mx, o));
    float e0 = __expf(v0.x-mx), e1 = __expf(v0.y-mx), e2 = __expf(v0.z-mx), e3 = __expf(v0.w-mx);
    float sm = e0+e1+e2+e3;
    #pragma unroll
    for(int o = 32; o >= 1; o >>= 1) sm += __shfl_xor(sm, o);
    *(float4*)(base + l * 4) = make_float4(e0,e1,e2,e3);
    if(l == 0){
      pms[(((size_t)b * 16 + c) * 8 + s) * 2    ] = mx;
      pms[(((size_t)b * 16 + c) * 8 + s) * 2 + 1] = sm;
    }
  }
  __syncthreads();

  // P fragments (rows m>=8 zero)
  short8 pa[8];
  #pragma unroll
  for(int kk = 0; kk < 8; ++kk){
    if(m < 8){
      const float* pp = ls + m * LSP2 + kk * 32 + (lg << 3);
      int4 pv = make_int4((int)pk2(pp[0],pp[1]), (int)pk2(pp[2],pp[3]),
                          (int)pk2(pp[4],pp[5]), (int)pk2(pp[6],pp[7]));
      pa[kk] = __builtin_bit_cast(short8, pv);
    } else {
      pa[kk] = (short8){0,0,0,0,0,0,0,0};
    }
  }
  __syncthreads();   // ls fully consumed; xv (alias) may now be written

  // PV: 4 x 64-n subtiles; warp-private staging (no barriers); prefetched loads.
  f32x4 acc[4];
  #pragma unroll
  for(int dt = 0; dt < 4; ++dt) acc[dt] = (f32x4){0,0,0,0};
  const int p = t & 31, db = t >> 5;

  uint4 va0, va1, va2, va3, vb0, vb1, vb2, vb3;
  {
    const unsigned short* rA = xb + (size_t)(2 * p) * DD + db * 32;
    const unsigned short* rB = rA + DD;
    va0 = *(const uint4*)(rA);      vb0 = *(const uint4*)(rB);
    va1 = *(const uint4*)(rA + 8);  vb1 = *(const uint4*)(rB + 8);
    va2 = *(const uint4*)(rA + 16); vb2 = *(const uint4*)(rB + 16);
    va3 = *(const uint4*)(rA + 24); vb3 = *(const uint4*)(rB + 24);
  }

  for(int ng = 0; ng < 4; ++ng){
    {
      uint4 VA[4] = {va0, va1, va2, va3};
      uint4 VB[4] = {vb0, vb1, vb2, vb3};
      #pragma unroll
      for(int q = 0; q < 4; ++q){
        unsigned int wa[4] = {VA[q].x, VA[q].y, VA[q].z, VA[q].w};
        unsigned int wb[4] = {VB[q].x, VB[q].y, VB[q].z, VB[q].w};
        #pragma unroll
        for(int h = 0; h < 4; ++h){
          int d0 = db * 32 + q * 8 + h * 2;
          unsigned int a = wa[h], bv = wb[h];
          unsigned int v0 = (a & 0xFFFFu) | (bv << 16);
          unsigned int v1 = (a >> 16) | (bv & 0xFFFF0000u);
          *(unsigned int*)(xv + d0 * 128 + ((p * 4) ^ ((d0 & 7) << 4))) = v0;
          int d1 = d0 + 1;
          *(unsigned int*)(xv + d1 * 128 + ((p * 4) ^ ((d1 & 7) << 4))) = v1;
        }
      }
    }
    if(ng < 3){
      const unsigned short* rA = xb + (size_t)((ng + 1) * 64 + 2 * p) * DD + db * 32;
      const unsigned short* rB = rA + DD;
      va0 = *(const uint4*)(rA);      vb0 = *(const uint4*)(rB);
      va1 = *(const uint4*)(rA + 8);  vb1 = *(const uint4*)(rB + 8);
      va2 = *(const uint4*)(rA + 16); vb2 = *(const uint4*)(rB + 16);
      va3 = *(const uint4*)(rA + 24); vb3 = *(const uint4*)(rB + 24);
    }
    __builtin_amdgcn_s_setprio(1);
    #pragma unroll
    for(int kkloc = 0; kkloc < 2; ++kkloc){
      int kk = ng * 2 + kkloc;
      #pragma unroll
      for(int dt = 0; dt < 4; ++dt){
        int d = w * 64 + dt * 16 + m;
        short8 bv = *(const short8*)(xv + d * 128 + ((kkloc * 64 + lg * 16) ^ ((d & 7) << 4)));
        acc[dt] = MFMA(pa[kk], bv, acc[dt]);
      }
    }
    __builtin_amdgcn_s_setprio(0);
  }
  if(l < 32){
    int s4 = lg * 4;
    #pragma unroll
    for(int dt = 0; dt < 4; ++dt){
      int d0 = w * 64 + dt * 16;
      #pragma unroll
      for(int j = 0; j < 4; ++j)
        pupd[((size_t)b * 16 + c) * 2048 + (s4 + j) * 256 + d0 + m] = acc[dt][j];
    }
  }
}

// Combine PX partials (16 chunks) -> PX/Z ; GRU ; residual MLP ; slots ; LN ; next qk
__global__ __launch_bounds__(1024, 1) void update_kernel(
    const float* __restrict__ pupd, const float* __restrict__ pms,
    float* __restrict__ slots, float* __restrict__ qbuf,
    const short8* __restrict__ mp, const short8* __restrict__ whh,
    const float* __restrict__ bih, const float* __restrict__ bhh,
    const short8* __restrict__ w1p, const float* __restrict__ b1v,
    const short8* __restrict__ w2p, const float* __restrict__ b2v,
    const float* __restrict__ lnsg, const float* __restrict__ lnsb,
    const float* __restrict__ lnmg, const float* __restrict__ lnmb,
    const short8* __restrict__ wqkp,
    float* __restrict__ dout, const int last)
{
  const int b = blockIdx.x, t = threadIdx.x, w = t >> 6, l = t & 63;
  __shared__ unsigned short A1[16 * 256];
  __shared__ unsigned short A2[16 * 256];
  __shared__ unsigned short A3[16 * 512];
  __shared__ float GR[8 * 256], GZ[8 * 256], GXN[8 * 256], GHN[8 * 256];
  __shared__ float SL[8 * 256];
  __shared__ float PMS[256];

  if(t < 256) PMS[t] = pms[(size_t)b * 256 + t];
  __syncthreads();

  const int col = t & 255, sg = t >> 8;
  float upd[2], pv[2];
  #pragma unroll
  for(int ss = 0; ss < 2; ++ss){
    int s = sg * 2 + ss;
    float mx = -1e30f;
    #pragma unroll
    for(int cc = 0; cc < 16; ++cc) mx = fmaxf(mx, PMS[(cc * 8 + s) * 2]);
    float Z = 0.f, u = 0.f;
    #pragma unroll
    for(int cc = 0; cc < 16; ++cc){
      float e = __expf(PMS[(cc * 8 + s) * 2] - mx);
      Z += e * PMS[(cc * 8 + s) * 2 + 1];
      u += e * pupd[((size_t)b * 16 + cc) * 2048 + s * 256 + col];
    }
    upd[ss] = u / Z;
    pv[ss]  = slots[(size_t)b * 2048 + s * 256 + col];
  }
  #pragma unroll
  for(int ss = 0; ss < 2; ++ss){
    int s = sg * 2 + ss;
    int byte = s * 512 + ((col * 2) ^ ((s & 7) << 4));
    *(unsigned short*)((char*)A1 + byte) = f2bf(upd[ss]);
    *(unsigned short*)((char*)A2 + byte) = f2bf(pv[ss]);
  }
  __syncthreads();

  {
    const int mq = l & 15;
    short8 a1f[8], a2f[8];
    #pragma unroll
    for(int kk = 0; kk < 8; ++kk){
      int ab = mq * 512 + (((kk * 64) + ((l >> 4) << 4)) ^ ((mq & 7) << 4));
      a1f[kk] = *(const short8*)((const char*)A1 + ab);
      a2f[kk] = *(const short8*)((const char*)A2 + ab);
    }
    #pragma unroll
    for(int i = 0; i < 3; ++i){
      int et = w + i * 16;
      f32x4 c1 = (f32x4){0,0,0,0}, c2 = (f32x4){0,0,0,0};
      #pragma unroll
      for(int kk = 0; kk < 8; ++kk){
        c1 = MFMA(a1f[kk], mp[((kk * 48 + et) << 6) + l], c1);
        c2 = MFMA(a2f[kk], whh[((kk * 48 + et) << 6) + l], c2);
      }
      int e = et * 16 + (l & 15);
      float xb = bih[e], hb = bhh[e];
      #pragma unroll
      for(int j = 0; j < 4; ++j){
        int s = ((l >> 4) << 2) + j;
        if(s < 8){
          float xx = c1[j] + xb, h = c2[j] + hb;
          if(i == 0)      GR[s * 256 + e      ] = 1.f/(1.f + __expf(-(xx + h)));
          else if(i == 1) GZ[s * 256 + (e-256)] = 1.f/(1.f + __expf(-(xx + h)));
          else { GXN[s * 256 + (e-512)] = xx; GHN[s * 256 + (e-512)] = h; }
        }
      }
    }
  }
  __syncthreads();

  #pragma unroll
  for(int ss = 0; ss < 2; ++ss){
    int s = sg * 2 + ss, idx = s * 256 + col;
    float r = GR[idx], z = GZ[idx], xn = GXN[idx], hn = GHN[idx];
    float nn = tanhf(xn + r * hn);
    SL[idx] = (1.f - z) * nn + z * pv[ss];
  }
  __syncthreads();

  if(w < 8){
    float4 g4 = ((const float4*)lnmg)[l], bb4 = ((const float4*)lnmb)[l];
    int s = w;
    float4 x4 = ((const float4*)(SL + s * 256))[l];
    float s1 = x4.x + x4.y + x4.z + x4.w;
    float s2 = x4.x*x4.x + x4.y*x4.y + x4.z*x4.z + x4.w*x4.w;
    #pragma unroll
    for(int o = 32; o >= 1; o >>= 1){ s1 += __shfl_xor(s1, o); s2 += __shfl_xor(s2, o); }
    float mean = s1 * (1.0f/256.0f);
    float inv  = rsqrtf(s2 * (1.0f/256.0f) - mean*mean + 1e-5f);
    float y0 = (x4.x-mean)*inv*g4.x + bb4.x;
    float y1 = (x4.y-mean)*inv*g4.y + bb4.y;
    float y2 = (x4.z-mean)*inv*g4.z + bb4.z;
    float y3 = (x4.w-mean)*inv*g4.w + bb4.w;
    int byte = s * 512 + ((l * 8) ^ ((s & 7) << 4));
    *(uint2*)((char*)A1 + byte) = make_uint2(pk2(y0,y1), pk2(y2,y3));
  }
  __syncthreads();

  {
    const int mq = l & 15;
    short8 af[8];
    #pragma unroll
    for(int kk = 0; kk < 8; ++kk){
      int ab = mq * 512 + (((kk * 64) + ((l >> 4) << 4)) ^ ((mq & 7) << 4));
      af[kk] = *(const short8*)((const char*)A1 + ab);
    }
    #pragma unroll
    for(int i = 0; i < 2; ++i){
      int et = w + i * 16;
      f32x4 cc = (f32x4){0,0,0,0};
      #pragma unroll
      for(int kk = 0; kk < 8; ++kk) cc = MFMA(af[kk], w1p[((kk * 32 + et) << 6) + l], cc);
      int e = et * 16 + (l & 15);
      float bb = b1v[e];
      #pragma unroll
      for(int j = 0; j < 4; ++j){
        int s = ((l >> 4) << 2) + j;
        if(s < 8){
          float h = fmaxf(cc[j] + bb, 0.f);
          int byte = s * 1024 + ((e * 2) ^ ((s & 7) << 4));
          *(unsigned short*)((char*)A3 + byte) = f2bf(h);
        }
      }
    }
  }
  __syncthreads();

  {
    const int mq = l & 15;
    short8 af[16];
    #pragma unroll
    for(int kk = 0; kk < 16; ++kk){
      int ab = mq * 1024 + (((kk * 64) + ((l >> 4) << 4)) ^ ((mq & 7) << 4));
      af[kk] = *(const short8*)((const char*)A3 + ab);
    }
    {
      int et = w;
      f32x4 cc = (f32x4){0,0,0,0};
      #pragma unroll
      for(int kk = 0; kk < 16; ++kk) cc = MFMA(af[kk], w2p[((kk * 16 + et) << 6) + l], cc);
      int e = et * 16 + (l & 15);
      float bb = b2v[e];
      #pragma unroll
      for(int j = 0; j < 4; ++j){
        int s = ((l >> 4) << 2) + j;
        if(s < 8) GR[s * 256 + e] = SL[s * 256 + e] + cc[j] + bb;
      }
    }
  }
  __syncthreads();

  for(int i = t; i < 2048; i += 1024){
    float v = GR[i];
    slots[(size_t)b * 2048 + i] = v;
    if(last) dout[(size_t)b * 2048 + i] = v;
  }
  if(w < 8){
    float4 g4 = ((const float4*)lnsg)[l], bb4 = ((const float4*)lnsb)[l];
    int s = w;
    float4 x4 = ((const float4*)(GR + s * 256))[l];
    float s1 = x4.x + x4.y + x4.z + x4.w;
    float s2 = x4.x*x4.x + x4.y*x4.y + x4.z*x4.z + x4.w*x4.w;
    #pragma unroll
    for(int o = 32; o >= 1; o >>= 1){ s1 += __shfl_xor(s1, o); s2 += __shfl_xor(s2, o); }
    float mean = s1 * (1.0f/256.0f);
    float inv  = rsqrtf(s2 * (1.0f/256.0f) - mean*mean + 1e-5f);
    float y0 = (x4.x-mean)*inv*g4.x + bb4.x;
    float y1 = (x4.y-mean)*inv*g4.y + bb4.y;
    float y2 = (x4.z-mean)*inv*g4.z + bb4.z;
    float y3 = (x4.w-mean)*inv*g4.w + bb4.w;
    int byte = s * 512 + ((l * 8) ^ ((s & 7) << 4));
    *(uint2*)((char*)A1 + byte) = make_uint2(pk2(y0,y1), pk2(y2,y3));
  }
  __syncthreads();
  {
    const int mq = l & 15;
    short8 af[8];
    #pragma unroll
    for(int kk = 0; kk < 8; ++kk){
      int ab = mq * 512 + (((kk * 64) + ((l >> 4) << 4)) ^ ((mq & 7) << 4));
      af[kk] = *(const short8*)((const char*)A1 + ab);
    }
    {
      int et = w;
      f32x4 cc = (f32x4){0,0,0,0};
      #pragma unroll
      for(int kk = 0; kk < 8; ++kk) cc = MFMA(af[kk], wqkp[((kk * 16 + et) << 6) + l], cc);
      int e = et * 16 + (l & 15);
      #pragma unroll
      for(int j = 0; j < 4; ++j){
        int s = ((l >> 4) << 2) + j;
        if(s < 8) qbuf[(size_t)b * 2048 + s * 256 + e] = cc[j];
      }
    }
  }
}

extern "C" void kernel_launch(void* const* d_in, const int* in_sizes, int n_in,
                              void* d_out, int out_size, void* d_ws, size_t ws_size,
                              hipStream_t stream)
{
  const float* inp   = (const float*)d_in[0];
  const float* noise = (const float*)d_in[1];
  const float* mu    = (const float*)d_in[2];
  const float* lsg   = (const float*)d_in[3];
  const float* lngi  = (const float*)d_in[4];
  const float* lnbi  = (const float*)d_in[5];
  const float* lngs  = (const float*)d_in[6];
  const float* lnbs  = (const float*)d_in[7];
  const float* lngm  = (const float*)d_in[8];
  const float* lnbm  = (const float*)d_in[9];
  const float* Wq    = (const float*)d_in[10];
  const float* Wk    = (const float*)d_in[11];
  const float* Wv    = (const float*)d_in[12];
  const float* Wih   = (const float*)d_in[13];
  const float* Whh   = (const float*)d_in[14];
  const float* bih   = (const float*)d_in[15];
  const float* bhh   = (const float*)d_in[16];
  const float* W1    = (const float*)d_in[17];
  const float* b1    = (const float*)d_in[18];
  const float* W2    = (const float*)d_in[19];
  const float* b2    = (const float*)d_in[20];
  float* dout = (float*)d_out;

  char* ws = (char*)d_ws;
  size_t off = 0;
  unsigned short* x   = (unsigned short*)(ws + off); off += (size_t)BB*NN*DD*2;
  short8* wqkp= (short8*)(ws + off); off += (size_t)256*256*2;
  short8* mp  = (short8*)(ws + off); off += (size_t)768*256*2;
  short8* whhp= (short8*)(ws + off); off += (size_t)768*256*2;
  short8* w1p = (short8*)(ws + off); off += (size_t)512*256*2;
  short8* w2p = (short8*)(ws + off); off += (size_t)256*512*2;
  float* wqkT = (float*)(ws + off);  off += (size_t)256*256*4;
  float* mf32 = (float*)(ws + off);  off += (size_t)768*256*4;
  float* qbuf = (float*)(ws + off);  off += (size_t)512*256*4;
  float* slots= (float*)(ws + off);  off += (size_t)512*256*4;
  float* pupd = (float*)(ws + off);  off += (size_t)BB*NCH*2048*4;
  float* pms  = (float*)(ws + off);  off += (size_t)BB*NCH*8*2*4;

  pre_kernel<<<1024, 256, 0, stream>>>(Wq, Wk, Wih, Wv, wqkT, mf32);

  PackDesc pd;
  const float* srcs[5] = {wqkT, mf32, Whh, W1, W2};
  unsigned short* dsts[5] = {(unsigned short*)wqkp, (unsigned short*)mp,
                             (unsigned short*)whhp, (unsigned short*)w1p,
                             (unsigned short*)w2p};
  int ets[5] = {16, 48, 48, 32, 16};
  int ks [5] = {256, 256, 256, 256, 512};
  int cum = 0;
  for(int i = 0; i < 5; ++i){
    pd.src[i] = srcs[i]; pd.dst[i] = dsts[i]; pd.ET[i] = ets[i]; pd.K[i] = ks[i];
    pd.blkStart[i] = cum;
    cum += (ets[i] * 16 * ks[i] + 255) / 256;
  }
  pd.blkStart[5] = cum;
  pack_all_kernel<<<cum, 256, 0, stream>>>(pd);

  ln_kernel<<<4096, 256, 0, stream>>>(inp, lngi, lnbi, x);
  init_kernel<<<64, 256, 0, stream>>>(noise, mu, lsg, lngs, lnbs, wqkp, slots, qbuf);

  for(int it = 0; it < 3; ++it){
    attn_kernel<<<BB * NCH, 256, 0, stream>>>(x, qbuf, pupd, pms);
    update_kernel<<<64, 1024, 0, stream>>>(pupd, pms, slots, qbuf, mp, whhp,
        bih, bhh, w1p, b1, w2p, b2, lngs, lnbs, lngm, lnbm, wqkp, dout, (it == 2) ? 1 : 0);
  }
}